// Round 14
// baseline (1031.581 us; speedup 1.0000x reference)
//
#include <hip/hip_runtime.h>

#define NN 100000
#define NE 1600000
#define TPB 256

// block counts
#define NB_MP8    782    // ceil(NN*2/256)
#define NB_TAGI   3125   // NN*8/256
#define NB_SAGE1  6272   // 392*16
#define NB_TAG    3125   // NN*8/256
#define NB_MP128T 3125   // NN/32
#define NB_TAG1K  782    // ceil(NN*8/1024)
#define NB_SAGE2F 3136
#define NB_RED    391    // ceil(NN/256)
#define NB_PROP   3125   // NN*8/256
#define NB_SAGE3  3125   // NN*8/256

// ---------------------------------------------------------------- CSR build
__global__ void k_init(int* __restrict__ deg, int* __restrict__ cursor, int* __restrict__ counter) {
    int i = blockIdx.x * TPB + threadIdx.x;
    if (i < NN) { deg[i] = 0; cursor[i] = 0; }
    if (i == 0) counter[0] = 0;
}

__global__ void k_deg(const int* __restrict__ dst, int* __restrict__ deg) {
    int e = blockIdx.x * TPB + threadIdx.x;
    if (e < NE) atomicAdd(&deg[dst[e]], 1);
}

__global__ void k_prep(const int* __restrict__ deg, float* __restrict__ inv_deg,
                       float* __restrict__ dinv, int* __restrict__ row_start,
                       int* __restrict__ counter) {
    int i = blockIdx.x * TPB + threadIdx.x;
    int lane = threadIdx.x & 63;
    int d = (i < NN) ? deg[i] : 0;
    int incl = d;
    #pragma unroll
    for (int o = 1; o < 64; o <<= 1) {
        int v = __shfl_up(incl, o, 64);
        if (lane >= o) incl += v;
    }
    int total = __shfl(incl, 63, 64);
    int base = 0;
    if (lane == 63) base = atomicAdd(counter, total);
    base = __shfl(base, 63, 64);
    if (i < NN) {
        row_start[i] = base + incl - d;
        inv_deg[i] = d > 0 ? 1.0f / (float)d : 0.0f;
        dinv[i]    = d > 0 ? 1.0f / sqrtf((float)d) : 0.0f;
    }
}

__global__ void k_fill(const int* __restrict__ src, const int* __restrict__ dst,
                       const int* __restrict__ row_start, int* __restrict__ cursor,
                       int* __restrict__ col) {
    int e = blockIdx.x * TPB + threadIdx.x;
    if (e < NE) {
        int d = dst[e];
        int p = atomicAdd(&cursor[d], 1);
        col[row_start[d] + p] = src[e];
    }
}

// ---------------------------------------------------------------- device parts
__device__ __forceinline__ void dev_meanprop8(int t, const float* __restrict__ h,
        const int* __restrict__ row_start, const int* __restrict__ deg,
        const float* __restrict__ inv_deg, const int* __restrict__ col,
        float* __restrict__ out) {
    if (t >= NN * 2) return;
    int n = t >> 1, half = t & 1;
    int rs = row_start[n], end = rs + deg[n];
    const float4* h4 = (const float4*)h;
    float4 s0 = make_float4(0,0,0,0), s1 = make_float4(0,0,0,0);
    int e = rs + half;
    for (; e + 2 < end; e += 4) {
        int c0 = col[e] * 2, c1 = col[e + 2] * 2;
        float4 a0 = h4[c0], a1 = h4[c0 + 1], b0 = h4[c1], b1 = h4[c1 + 1];
        s0.x += a0.x + b0.x; s0.y += a0.y + b0.y; s0.z += a0.z + b0.z; s0.w += a0.w + b0.w;
        s1.x += a1.x + b1.x; s1.y += a1.y + b1.y; s1.z += a1.z + b1.z; s1.w += a1.w + b1.w;
    }
    if (e < end) {
        int c0 = col[e] * 2;
        float4 a0 = h4[c0], a1 = h4[c0 + 1];
        s0.x += a0.x; s0.y += a0.y; s0.z += a0.z; s0.w += a0.w;
        s1.x += a1.x; s1.y += a1.y; s1.z += a1.z; s1.w += a1.w;
    }
    s0.x += __shfl_xor(s0.x, 1, 64); s0.y += __shfl_xor(s0.y, 1, 64);
    s0.z += __shfl_xor(s0.z, 1, 64); s0.w += __shfl_xor(s0.w, 1, 64);
    s1.x += __shfl_xor(s1.x, 1, 64); s1.y += __shfl_xor(s1.y, 1, 64);
    s1.z += __shfl_xor(s1.z, 1, 64); s1.w += __shfl_xor(s1.w, 1, 64);
    float w = inv_deg[n];
    float4 o = (half == 0) ? s0 : s1;
    o.x *= w; o.y *= w; o.z *= w; o.w *= w;
    ((float4*)out)[n * 2 + half] = o;
}

__device__ __forceinline__ void dev_taginit(int t, const float* __restrict__ x,
        const float* __restrict__ TaW, const float* __restrict__ TbW,
        const float* __restrict__ dinv, float* __restrict__ outa,
        float* __restrict__ outb, float* __restrict__ q0) {
    if (t >= NN * 8) return;
    int n = t >> 3, o = t & 7;
    const float* xr = x + (size_t)n * 8;
    float sa = 0.f, sb = 0.f;
    #pragma unroll
    for (int j = 0; j < 8; ++j) {
        float v = xr[j];
        sa += v * TaW[j * 8 + o];
        sb += v * TbW[j * 8 + o];
    }
    outa[t] = sa;
    outb[t] = sb;
    q0[t] = xr[o] * dinv[n];
}

__device__ __forceinline__ void dev_tagstep(int t, const float* __restrict__ q,
        const int* __restrict__ row_start, const int* __restrict__ deg,
        const float* __restrict__ dinv, const int* __restrict__ col,
        float* __restrict__ qout, const float* __restrict__ Wa,
        const float* __restrict__ Wb, float* __restrict__ outa,
        float* __restrict__ outb, const float* __restrict__ ba,
        const float* __restrict__ bb, int fina, int finb) {
    if (t >= NN * 8) return;
    int n = t >> 3, qd = t & 7;
    int half = qd & 1, epar = qd >> 1;
    int rs = row_start[n], end = rs + deg[n];
    const float4* q4 = (const float4*)q;
    float4 s = make_float4(0,0,0,0);
    int e = rs + epar;
    for (; e + 4 < end; e += 8) {
        int c0 = col[e] * 2 + half, c1 = col[e + 4] * 2 + half;
        float4 a = q4[c0], b = q4[c1];
        s.x += a.x + b.x; s.y += a.y + b.y; s.z += a.z + b.z; s.w += a.w + b.w;
    }
    if (e < end) {
        float4 a = q4[col[e] * 2 + half];
        s.x += a.x; s.y += a.y; s.z += a.z; s.w += a.w;
    }
    #pragma unroll
    for (int o = 2; o < 8; o <<= 1) {
        s.x += __shfl_xor(s.x, o, 64); s.y += __shfl_xor(s.y, o, 64);
        s.z += __shfl_xor(s.z, o, 64); s.w += __shfl_xor(s.w, o, 64);
    }
    float dn = dinv[n];
    float m0 = s.x * dn, m1 = s.y * dn, m2 = s.z * dn, m3 = s.w * dn;
    if (qout && epar == 0) {
        ((float4*)qout)[n * 2 + half] = make_float4(m0 * dn, m1 * dn, m2 * dn, m3 * dn);
    }
    float o0 = __shfl_xor(m0, 1, 64), o1 = __shfl_xor(m1, 1, 64);
    float o2 = __shfl_xor(m2, 1, 64), o3 = __shfl_xor(m3, 1, 64);
    float h[8];
    if (half) {
        h[0] = o0; h[1] = o1; h[2] = o2; h[3] = o3;
        h[4] = m0; h[5] = m1; h[6] = m2; h[7] = m3;
    } else {
        h[0] = m0; h[1] = m1; h[2] = m2; h[3] = m3;
        h[4] = o0; h[5] = o1; h[6] = o2; h[7] = o3;
    }
    int f = qd;
    if (Wa) {
        float v = outa[(size_t)n * 8 + f];
        #pragma unroll
        for (int j = 0; j < 8; ++j) v += h[j] * Wa[j * 8 + f];
        if (fina) v = fmaxf(v + ba[f], 0.f);
        outa[(size_t)n * 8 + f] = v;
    }
    {
        float v = outb[(size_t)n * 8 + f];
        #pragma unroll
        for (int j = 0; j < 8; ++j) v += h[j] * Wb[j * 8 + f];
        if (finb) v = fmaxf(v + bb[f], 0.f);
        outb[(size_t)n * 8 + f] = v;
    }
}

__device__ __forceinline__ void dev_sage1(int bid, int tid, const float* __restrict__ a8,
        const float* __restrict__ x, const float* __restrict__ W1l,
        const float* __restrict__ W1r, const float* __restrict__ b1,
        float* __restrict__ x1, float* __restrict__ x1T) {
    int bx = bid >> 4, by = bid & 15;
    int n = bx * 256 + tid;
    int og = by * 8;
    int nc = (n < NN) ? n : (NN - 1);
    float acc[8];
    #pragma unroll
    for (int j = 0; j < 8; ++j) acc[j] = b1[og + j];
    const float* ar = a8 + (size_t)nc * 8;
    const float* xr = x + (size_t)nc * 8;
    #pragma unroll
    for (int k = 0; k < 8; ++k) {
        float av = ar[k], xv = xr[k];
        const float4* wl = (const float4*)(W1l + k * 128 + og);
        const float4* wr = (const float4*)(W1r + k * 128 + og);
        float4 l0 = wl[0], l1 = wl[1], r0 = wr[0], r1 = wr[1];
        acc[0] += av * l0.x + xv * r0.x;
        acc[1] += av * l0.y + xv * r0.y;
        acc[2] += av * l0.z + xv * r0.z;
        acc[3] += av * l0.w + xv * r0.w;
        acc[4] += av * l1.x + xv * r1.x;
        acc[5] += av * l1.y + xv * r1.y;
        acc[6] += av * l1.z + xv * r1.z;
        acc[7] += av * l1.w + xv * r1.w;
    }
    if (n < NN) {
        #pragma unroll
        for (int j = 0; j < 8; ++j) acc[j] = fmaxf(acc[j], 0.f);
        *(float4*)(x1 + (size_t)n * 128 + og)     = make_float4(acc[0], acc[1], acc[2], acc[3]);
        *(float4*)(x1 + (size_t)n * 128 + og + 4) = make_float4(acc[4], acc[5], acc[6], acc[7]);
        #pragma unroll
        for (int j = 0; j < 8; ++j)
            x1T[(size_t)(og + j) * NN + n] = acc[j];
    }
}

__device__ __forceinline__ void dev_meanprop128T(int bid, int tid, const float* __restrict__ h,
        const int* __restrict__ row_start, const int* __restrict__ deg,
        const float* __restrict__ inv_deg, const int* __restrict__ col,
        float* __restrict__ outT) {
    __shared__ float t[128][33];
    int n0 = bid * 32;
    int nl = tid >> 5;
    int f4 = tid & 31;
    int n = n0 + nl;
    int rs = row_start[n], end = rs + deg[n];
    const float4* h4 = (const float4*)h;
    float4 s = make_float4(0.f, 0.f, 0.f, 0.f);
    int e = rs;
    for (; e + 3 < end; e += 4) {
        float4 v0 = h4[(size_t)col[e] * 32 + f4];
        float4 v1 = h4[(size_t)col[e + 1] * 32 + f4];
        float4 v2 = h4[(size_t)col[e + 2] * 32 + f4];
        float4 v3 = h4[(size_t)col[e + 3] * 32 + f4];
        s.x += (v0.x + v1.x) + (v2.x + v3.x);
        s.y += (v0.y + v1.y) + (v2.y + v3.y);
        s.z += (v0.z + v1.z) + (v2.z + v3.z);
        s.w += (v0.w + v1.w) + (v2.w + v3.w);
    }
    for (; e < end; ++e) {
        float4 v = h4[(size_t)col[e] * 32 + f4];
        s.x += v.x; s.y += v.y; s.z += v.z; s.w += v.w;
    }
    float w = inv_deg[n];
    t[f4 * 4 + 0][nl] = s.x * w;
    t[f4 * 4 + 1][nl] = s.y * w;
    t[f4 * 4 + 2][nl] = s.z * w;
    t[f4 * 4 + 3][nl] = s.w * w;
    __syncthreads();
    int k = tid >> 3;
    int q = tid & 7;
    float4 v = make_float4(t[k][q * 4], t[k][q * 4 + 1], t[k][q * 4 + 2], t[k][q * 4 + 3]);
    *(float4*)(outT + (size_t)k * NN + n0 + q * 4) = v;
}

__device__ __forceinline__ void dev_sage2f(int bid, int tid, const float* __restrict__ aT,
        const float* __restrict__ xT, const float* __restrict__ W2l,
        const float* __restrict__ W2r, const float* __restrict__ b2,
        const float* __restrict__ W3l, const float* __restrict__ W3r,
        float* __restrict__ ylp, float* __restrict__ yrp) {
    int xcd = bid & 7;
    int s = bid >> 3;
    int xblk = xcd * 49 + (s >> 3);
    int ogq = s & 7;
    int og = ogq * 16;
    int n0 = xblk * 256 + tid;
    int n = (n0 < NN) ? n0 : (NN - 1);
    float acc[16];
    #pragma unroll
    for (int j = 0; j < 16; ++j) acc[j] = b2[og + j];
    const float* ap = aT + n;
    const float* xp = xT + n;
    const float* wlp = W2l + og;
    const float* wrp = W2r + og;
    #pragma unroll 4
    for (int k = 0; k < 128; ++k) {
        float a = ap[0], xv = xp[0];
        ap += NN; xp += NN;
        const float4* wl4 = (const float4*)(wlp + (k << 7));
        const float4* wr4 = (const float4*)(wrp + (k << 7));
        #pragma unroll
        for (int q = 0; q < 4; ++q) {
            float4 wl = wl4[q], wr = wr4[q];
            acc[q * 4 + 0] += a * wl.x + xv * wr.x;
            acc[q * 4 + 1] += a * wl.y + xv * wr.y;
            acc[q * 4 + 2] += a * wl.z + xv * wr.z;
            acc[q * 4 + 3] += a * wl.w + xv * wr.w;
        }
    }
    float pl = 0.f, pr = 0.f;
    #pragma unroll
    for (int j = 0; j < 16; ++j) {
        float v = fmaxf(acc[j], 0.f);
        pl += v * W3l[og + j];
        pr += v * W3r[og + j];
    }
    if (n0 < NN) {
        ylp[(size_t)ogq * NN + n0] = pl;
        yrp[(size_t)ogq * NN + n0] = pr;
    }
}

__device__ __forceinline__ void dev_red8(int t, const float* __restrict__ ylp,
        const float* __restrict__ yrp, float* __restrict__ yl, float* __restrict__ yr) {
    if (t >= NN) return;
    float sl = 0.f, sr = 0.f;
    #pragma unroll
    for (int j = 0; j < 8; ++j) {
        sl += ylp[(size_t)j * NN + t];
        sr += yrp[(size_t)j * NN + t];
    }
    yl[t] = sl;
    yr[t] = sr;
}

// TAGa layer-2 projection: ya[0..2], seed qa0 = (ha@TaW2[3])*dinv
__device__ __forceinline__ void dev_projA(int t, const float* __restrict__ outa,
        const float* __restrict__ TaW2, float* __restrict__ ya,
        const float* __restrict__ dinv, float* __restrict__ qa0) {
    if (t >= NN) return;
    float dn = dinv[t];
    float ha[8];
    #pragma unroll
    for (int j = 0; j < 8; ++j) ha[j] = outa[(size_t)t * 8 + j];
    #pragma unroll
    for (int k = 0; k < 4; ++k) {
        float s = 0.f;
        #pragma unroll
        for (int j = 0; j < 8; ++j) s += ha[j] * TaW2[k * 8 + j];
        if (k == 3) qa0[t] = s * dn;
        else        ya[(size_t)k * NN + t] = s;
    }
}

__device__ __forceinline__ void dev_sage3(int t, const float* __restrict__ yl,
        const float* __restrict__ yr, const int* __restrict__ row_start,
        const int* __restrict__ deg, const float* __restrict__ inv_deg,
        const int* __restrict__ col, const float* __restrict__ b3,
        float* __restrict__ x1f) {
    if (t >= NN * 8) return;
    int n = t >> 3, q = t & 7;
    int rs = row_start[n], d = deg[n];
    float s = 0.f;
    for (int e = rs + q; e < rs + d; e += 8) s += yl[col[e]];
    s += __shfl_xor(s, 1, 64);
    s += __shfl_xor(s, 2, 64);
    s += __shfl_xor(s, 4, 64);
    if (q == 0) x1f[n] = fmaxf(s * inv_deg[n] + yr[n] + b3[0], 0.f);
}

// scalar sym-prop Horner step, 8 thr/node; fout!=null -> final (relu+bias)
__device__ __forceinline__ void dev_symprop1(int t, const float* __restrict__ qin,
        const float* __restrict__ yk, const int* __restrict__ row_start,
        const int* __restrict__ deg, const float* __restrict__ dinv,
        const int* __restrict__ col, float* __restrict__ qout,
        float* __restrict__ fout, const float* __restrict__ bias) {
    if (t >= NN * 8) return;
    int n = t >> 3, qd = t & 7;
    int rs = row_start[n], d = deg[n];
    float s = 0.f;
    for (int e = rs + qd; e < rs + d; e += 8) s += qin[col[e]];
    s += __shfl_xor(s, 1, 64);
    s += __shfl_xor(s, 2, 64);
    s += __shfl_xor(s, 4, 64);
    if (qd == 0) {
        float dn = dinv[n];
        float v = dn * s + yk[n];
        if (fout) fout[n] = fmaxf(v + bias[0], 0.f);
        else      qout[n] = dn * v;
    }
}

// ---------------------------------------------------------------- union kernels
__global__ __launch_bounds__(256) void k_u1(const float* x, const int* row_start,
        const int* deg, const float* inv_deg, const float* dinv, const int* col,
        float* a8, const float* TaW1, const float* TbW1, float* outa, float* outb, float* qA) {
    if (blockIdx.x < NB_MP8)
        dev_meanprop8(blockIdx.x * 256 + threadIdx.x, x, row_start, deg, inv_deg, col, a8);
    else
        dev_taginit((blockIdx.x - NB_MP8) * 256 + threadIdx.x, x, TaW1, TbW1, dinv, outa, outb, qA);
}

__global__ __launch_bounds__(256) void k_u2(const float* a8, const float* x,
        const float* W1l, const float* W1r, const float* b1, float* x1, float* x1T,
        const float* qA, const int* row_start, const int* deg, const float* dinv,
        const int* col, float* qB, const float* TaW1, const float* TbW1,
        float* outa, float* outb) {
    if (blockIdx.x < NB_SAGE1)
        dev_sage1(blockIdx.x, threadIdx.x, a8, x, W1l, W1r, b1, x1, x1T);
    else
        dev_tagstep((blockIdx.x - NB_SAGE1) * 256 + threadIdx.x, qA, row_start, deg, dinv,
                    col, qB, TaW1 + 64, TbW1 + 64, outa, outb, nullptr, nullptr, 0, 0);
}

__global__ __launch_bounds__(1024) void k_u3(const float* x1, const int* row_start,
        const int* deg, const float* inv_deg, const float* dinv, const int* col,
        float* a128T, const float* qB, float* qA, const float* TaW1, const float* TbW1,
        float* outa, float* outb) {
    if (blockIdx.x < NB_MP128T)
        dev_meanprop128T(blockIdx.x, threadIdx.x, x1, row_start, deg, inv_deg, col, a128T);
    else
        dev_tagstep((blockIdx.x - NB_MP128T) * 1024 + threadIdx.x, qB, row_start, deg, dinv,
                    col, qA, TaW1 + 2 * 64, TbW1 + 2 * 64, outa, outb, nullptr, nullptr, 0, 0);
}

__global__ __launch_bounds__(256) void k_u4(const float* a128T, const float* x1T,
        const float* W2l, const float* W2r, const float* b2, const float* W3l,
        const float* W3r, float* ylp, float* yrp,
        const float* qA, const int* row_start, const int* deg, const float* dinv,
        const int* col, float* qB, const float* TaW1, const float* TbW1,
        float* outa, float* outb, const float* TaB1) {
    if (blockIdx.x < NB_SAGE2F)
        dev_sage2f(blockIdx.x, threadIdx.x, a128T, x1T, W2l, W2r, b2, W3l, W3r, ylp, yrp);
    else
        dev_tagstep((blockIdx.x - NB_SAGE2F) * 256 + threadIdx.x, qA, row_start, deg, dinv,
                    col, qB, TaW1 + 3 * 64, TbW1 + 3 * 64, outa, outb, TaB1, nullptr, 1, 0);
}

__global__ __launch_bounds__(256) void k_u5(const float* ylp, const float* yrp,
        float* yl, float* yr, const float* outa, const float* TaW2, float* ya,
        const float* dinv, float* qa0) {
    if (blockIdx.x < NB_RED)
        dev_red8(blockIdx.x * 256 + threadIdx.x, ylp, yrp, yl, yr);
    else
        dev_projA((blockIdx.x - NB_RED) * 256 + threadIdx.x, outa, TaW2, ya, dinv, qa0);
}

__global__ __launch_bounds__(256) void k_u6(const float* yl, const float* yr,
        const int* row_start, const int* deg, const float* inv_deg, const float* dinv,
        const int* col, const float* b3, float* x1f,
        const float* qB, float* qA, const float* TbW1, float* outa, float* outb) {
    if (blockIdx.x < NB_SAGE3)
        dev_sage3(blockIdx.x * 256 + threadIdx.x, yl, yr, row_start, deg, inv_deg, col, b3, x1f);
    else
        dev_tagstep((blockIdx.x - NB_SAGE3) * 256 + threadIdx.x, qB, row_start, deg, dinv,
                    col, qA, nullptr, TbW1 + 4 * 64, outa, outb, nullptr, nullptr, 0, 0);
}

// aprop_i union tagstep_(i+4)
__global__ __launch_bounds__(256) void k_u7(const float* qa0, const float* ya2,
        const int* row_start, const int* deg, const float* dinv, const int* col,
        float* tA, const float* qA, float* qB, const float* TbW1,
        float* outa, float* outb) {
    if (blockIdx.x < NB_PROP)
        dev_symprop1(blockIdx.x * 256 + threadIdx.x, qa0, ya2, row_start, deg, dinv, col,
                     tA, nullptr, nullptr);
    else
        dev_tagstep((blockIdx.x - NB_PROP) * 256 + threadIdx.x, qA, row_start, deg, dinv,
                    col, qB, nullptr, TbW1 + 5 * 64, outa, outb, nullptr, nullptr, 0, 0);
}

__global__ __launch_bounds__(256) void k_u8(const float* tA, const float* ya1,
        const int* row_start, const int* deg, const float* dinv, const int* col,
        float* tB, const float* qB, float* qA, const float* TbW1,
        float* outa, float* outb) {
    if (blockIdx.x < NB_PROP)
        dev_symprop1(blockIdx.x * 256 + threadIdx.x, tA, ya1, row_start, deg, dinv, col,
                     tB, nullptr, nullptr);
    else
        dev_tagstep((blockIdx.x - NB_PROP) * 256 + threadIdx.x, qB, row_start, deg, dinv,
                    col, qA, nullptr, TbW1 + 6 * 64, outa, outb, nullptr, nullptr, 0, 0);
}

__global__ __launch_bounds__(256) void k_u9(const float* tB, const float* ya0,
        const int* row_start, const int* deg, const float* dinv, const int* col,
        float* x2s, const float* TaB2, const float* qA, float* qB, const float* TbW1,
        float* outa, float* outb) {
    if (blockIdx.x < NB_PROP)
        dev_symprop1(blockIdx.x * 256 + threadIdx.x, tB, ya0, row_start, deg, dinv, col,
                     nullptr, x2s, TaB2);
    else
        dev_tagstep((blockIdx.x - NB_PROP) * 256 + threadIdx.x, qA, row_start, deg, dinv,
                    col, qB, nullptr, TbW1 + 7 * 64, outa, outb, nullptr, nullptr, 0, 0);
}

__global__ __launch_bounds__(256) void k_tag8(const float* qB, const int* row_start,
        const int* deg, const float* dinv, const int* col, float* qA,
        const float* TbW1, float* outa, float* outb) {
    dev_tagstep(blockIdx.x * 256 + threadIdx.x, qB, row_start, deg, dinv, col, qA,
                nullptr, TbW1 + 8 * 64, outa, outb, nullptr, nullptr, 0, 0);
}

__global__ __launch_bounds__(256) void k_tag9(const float* qA, const int* row_start,
        const int* deg, const float* dinv, const int* col,
        const float* TbW1, const float* TbB1, float* outa, float* outb) {
    dev_tagstep(blockIdx.x * 256 + threadIdx.x, qA, row_start, deg, dinv, col, nullptr,
                nullptr, TbW1 + 9 * 64, outa, outb, nullptr, TbB1, 0, 1);
}

__global__ __launch_bounds__(256) void k_projB(const float* __restrict__ outb,
        const float* __restrict__ TbW2, float* __restrict__ yb,
        const float* __restrict__ dinv, float* __restrict__ qb0) {
    int t = blockIdx.x * 256 + threadIdx.x;
    if (t >= NN) return;
    float dn = dinv[t];
    float hb[8];
    #pragma unroll
    for (int j = 0; j < 8; ++j) hb[j] = outb[(size_t)t * 8 + j];
    #pragma unroll
    for (int k = 0; k < 10; ++k) {
        float s = 0.f;
        #pragma unroll
        for (int j = 0; j < 8; ++j) s += hb[j] * TbW2[k * 8 + j];
        if (k == 9) qb0[t] = s * dn;
        else        yb[(size_t)k * NN + t] = s;
    }
}

__global__ __launch_bounds__(256) void k_bprop(const float* qin, const float* yk,
        const int* row_start, const int* deg, const float* dinv, const int* col,
        float* qout) {
    dev_symprop1(blockIdx.x * 256 + threadIdx.x, qin, yk, row_start, deg, dinv, col,
                 qout, nullptr, nullptr);
}

// final b Horner step + full output combine
__global__ __launch_bounds__(256) void k_bpropfin(const float* __restrict__ qin,
        const float* __restrict__ yb0, const int* __restrict__ row_start,
        const int* __restrict__ deg, const float* __restrict__ dinv,
        const int* __restrict__ col, const float* __restrict__ TbB2,
        const float* __restrict__ x2s, const float* __restrict__ x1f,
        const float* __restrict__ l2w, const float* __restrict__ l2b,
        const float* __restrict__ l1w, const float* __restrict__ l1b,
        float* __restrict__ out) {
    int t = blockIdx.x * 256 + threadIdx.x;
    if (t >= NN * 8) return;
    int n = t >> 3, qd = t & 7;
    int rs = row_start[n], d = deg[n];
    float s = 0.f;
    for (int e = rs + qd; e < rs + d; e += 8) s += qin[col[e]];
    s += __shfl_xor(s, 1, 64);
    s += __shfl_xor(s, 2, 64);
    s += __shfl_xor(s, 4, 64);
    if (qd == 0) {
        float dn = dinv[n];
        float x3 = fmaxf(dn * s + yb0[n] + TbB2[0], 0.f);
        float x23 = fmaxf(x2s[n] * l2w[0] + x3 * l2w[1] + l2b[0], 0.f);
        out[n] = fmaxf(x1f[n] * l1w[0] + x23 * l1w[1] + l1b[0], 0.f);
    }
}

// ---------------------------------------------------------------- host launch
#define GL(kern, n, ...) \
    kern<<<dim3((unsigned)(((long)(n) + TPB - 1) / TPB)), dim3(TPB), 0, stream>>>(__VA_ARGS__)

extern "C" void kernel_launch(void* const* d_in, const int* in_sizes, int n_in,
                              void* d_out, int out_size, void* d_ws, size_t ws_size,
                              hipStream_t stream) {
    (void)in_sizes; (void)n_in; (void)out_size; (void)ws_size;
    const float* x   = (const float*)d_in[0];
    const int*   ei  = (const int*)d_in[1];
    const int*   src = ei;
    const int*   dst = ei + NE;
    const float* W1l = (const float*)d_in[2];
    const float* W1r = (const float*)d_in[3];
    const float* b1  = (const float*)d_in[4];
    const float* W2l = (const float*)d_in[5];
    const float* W2r = (const float*)d_in[6];
    const float* b2  = (const float*)d_in[7];
    const float* W3l = (const float*)d_in[8];
    const float* W3r = (const float*)d_in[9];
    const float* b3  = (const float*)d_in[10];
    const float* TaW1 = (const float*)d_in[11];
    const float* TaB1 = (const float*)d_in[12];
    const float* TaW2 = (const float*)d_in[13];
    const float* TaB2 = (const float*)d_in[14];
    const float* TbW1 = (const float*)d_in[15];
    const float* TbB1 = (const float*)d_in[16];
    const float* TbW2 = (const float*)d_in[17];
    const float* TbB2 = (const float*)d_in[18];
    const float* l2w = (const float*)d_in[19];
    const float* l2b = (const float*)d_in[20];
    const float* l1w = (const float*)d_in[21];
    const float* l1b = (const float*)d_in[22];
    float* out = (float*)d_out;

    char* p = (char*)d_ws;
    size_t off = 0;
    auto alloc = [&](size_t bytes) -> void* {
        void* r = p + off;
        off = (off + bytes + 255) & ~(size_t)255;
        return r;
    };
    int*   deg       = (int*)  alloc((size_t)NN * 4);
    float* inv_deg   = (float*)alloc((size_t)NN * 4);
    float* dinv      = (float*)alloc((size_t)NN * 4);
    int*   row_start = (int*)  alloc((size_t)NN * 4);
    int*   cursor    = (int*)  alloc((size_t)NN * 4);
    int*   counter   = (int*)  alloc(256);
    int*   col       = (int*)  alloc((size_t)NE * 4);
    float* a8        = (float*)alloc((size_t)NN * 8 * 4);
    float* qA        = (float*)alloc((size_t)NN * 8 * 4);
    float* qB        = (float*)alloc((size_t)NN * 8 * 4);
    float* outa      = (float*)alloc((size_t)NN * 8 * 4);
    float* outb      = (float*)alloc((size_t)NN * 8 * 4);
    float* x1        = (float*)alloc((size_t)NN * 128 * 4);
    float* a128T     = (float*)alloc((size_t)NN * 128 * 4);
    float* x1T       = (float*)alloc((size_t)NN * 128 * 4);
    float* ylp       = (float*)alloc((size_t)NN * 8 * 4);
    float* yrp       = (float*)alloc((size_t)NN * 8 * 4);
    float* yl        = (float*)alloc((size_t)NN * 4);
    float* yr        = (float*)alloc((size_t)NN * 4);
    float* x1f       = (float*)alloc((size_t)NN * 4);
    float* x2s       = (float*)alloc((size_t)NN * 4);
    float* tA        = (float*)alloc((size_t)NN * 4);
    float* tB        = (float*)alloc((size_t)NN * 4);
    float* qa0       = (float*)alloc((size_t)NN * 4);
    float* qb0       = (float*)alloc((size_t)NN * 4);
    float* ya        = (float*)alloc((size_t)NN * 3 * 4);
    float* yb        = (float*)alloc((size_t)NN * 9 * 4);

    // CSR build (reused by all edge passes)
    GL(k_init, NN, deg, cursor, counter);
    GL(k_deg, NE, dst, deg);
    GL(k_prep, NN, deg, inv_deg, dinv, row_start, counter);
    GL(k_fill, NE, src, dst, row_start, cursor, col);

    // stage 1: meanprop8 ∪ taginit
    k_u1<<<dim3(NB_MP8 + NB_TAGI), dim3(256), 0, stream>>>(
        x, row_start, deg, inv_deg, dinv, col, a8, TaW1, TbW1, outa, outb, qA);
    // stage 2: sage1 ∪ tagstep1 (qA->qB)
    k_u2<<<dim3(NB_SAGE1 + NB_TAG), dim3(256), 0, stream>>>(
        a8, x, W1l, W1r, b1, x1, x1T, qA, row_start, deg, dinv, col, qB, TaW1, TbW1, outa, outb);
    // stage 3: meanprop128T ∪ tagstep2 (qB->qA)
    k_u3<<<dim3(NB_MP128T + NB_TAG1K), dim3(1024), 0, stream>>>(
        x1, row_start, deg, inv_deg, dinv, col, a128T, qB, qA, TaW1, TbW1, outa, outb);
    // stage 4: sage2f ∪ tagstep3 (qA->qB, finalize outa)
    k_u4<<<dim3(NB_SAGE2F + NB_TAG), dim3(256), 0, stream>>>(
        a128T, x1T, W2l, W2r, b2, W3l, W3r, ylp, yrp,
        qA, row_start, deg, dinv, col, qB, TaW1, TbW1, outa, outb, TaB1);
    // stage 5: red8 ∪ projA
    k_u5<<<dim3(NB_RED + NB_RED), dim3(256), 0, stream>>>(
        ylp, yrp, yl, yr, outa, TaW2, ya, dinv, qa0);
    // stage 6: sage3 ∪ tagstep4 (qB->qA)
    k_u6<<<dim3(NB_SAGE3 + NB_TAG), dim3(256), 0, stream>>>(
        yl, yr, row_start, deg, inv_deg, dinv, col, b3, x1f, qB, qA, TbW1, outa, outb);
    // stage 7: aprop1 (qa0->tA) ∪ tagstep5 (qA->qB)
    k_u7<<<dim3(NB_PROP + NB_TAG), dim3(256), 0, stream>>>(
        qa0, ya + 2 * NN, row_start, deg, dinv, col, tA, qA, qB, TbW1, outa, outb);
    // stage 8: aprop2 (tA->tB) ∪ tagstep6 (qB->qA)
    k_u8<<<dim3(NB_PROP + NB_TAG), dim3(256), 0, stream>>>(
        tA, ya + 1 * NN, row_start, deg, dinv, col, tB, qB, qA, TbW1, outa, outb);
    // stage 9: aprop3 (tB->x2s final) ∪ tagstep7 (qA->qB)
    k_u9<<<dim3(NB_PROP + NB_TAG), dim3(256), 0, stream>>>(
        tB, ya + 0 * NN, row_start, deg, dinv, col, x2s, TaB2, qA, qB, TbW1, outa, outb);
    // tagstep8 (qB->qA), tagstep9 (qA, finalize outb)
    k_tag8<<<dim3(NB_TAG), dim3(256), 0, stream>>>(qB, row_start, deg, dinv, col, qA, TbW1, outa, outb);
    k_tag9<<<dim3(NB_TAG), dim3(256), 0, stream>>>(qA, row_start, deg, dinv, col, TbW1, TbB1, outa, outb);
    // projB
    k_projB<<<dim3(NB_RED), dim3(256), 0, stream>>>(outb, TbW2, yb, dinv, qb0);
    // b Horner chain: qb0 -> tA -> tB -> ... (8 steps) -> final combine
    k_bprop<<<dim3(NB_PROP), dim3(256), 0, stream>>>(qb0, yb + 8 * NN, row_start, deg, dinv, col, tA);
    k_bprop<<<dim3(NB_PROP), dim3(256), 0, stream>>>(tA,  yb + 7 * NN, row_start, deg, dinv, col, tB);
    k_bprop<<<dim3(NB_PROP), dim3(256), 0, stream>>>(tB,  yb + 6 * NN, row_start, deg, dinv, col, tA);
    k_bprop<<<dim3(NB_PROP), dim3(256), 0, stream>>>(tA,  yb + 5 * NN, row_start, deg, dinv, col, tB);
    k_bprop<<<dim3(NB_PROP), dim3(256), 0, stream>>>(tB,  yb + 4 * NN, row_start, deg, dinv, col, tA);
    k_bprop<<<dim3(NB_PROP), dim3(256), 0, stream>>>(tA,  yb + 3 * NN, row_start, deg, dinv, col, tB);
    k_bprop<<<dim3(NB_PROP), dim3(256), 0, stream>>>(tB,  yb + 2 * NN, row_start, deg, dinv, col, tA);
    k_bprop<<<dim3(NB_PROP), dim3(256), 0, stream>>>(tA,  yb + 1 * NN, row_start, deg, dinv, col, tB);
    k_bpropfin<<<dim3(NB_PROP), dim3(256), 0, stream>>>(tB, yb + 0 * NN, row_start, deg, dinv, col,
        TbB2, x2s, x1f, l2w, l2b, l1w, l1b, out);
}

// Round 15
// 741.969 us; speedup vs baseline: 1.3903x; 1.3903x over previous
//
#include <hip/hip_runtime.h>

#define NN 100000
#define NE 1600000
#define TPB 256

// ---------------------------------------------------------------- CSR build
__global__ void k_init(int* __restrict__ deg, int* __restrict__ cursor, int* __restrict__ counter) {
    int i = blockIdx.x * TPB + threadIdx.x;
    if (i < NN) { deg[i] = 0; cursor[i] = 0; }
    if (i == 0) counter[0] = 0;
}

__global__ void k_deg(const int* __restrict__ dst, int* __restrict__ deg) {
    int e = blockIdx.x * TPB + threadIdx.x;
    if (e < NE) atomicAdd(&deg[dst[e]], 1);
}

// wave64 scan: one atomic per WAVE on the global counter
__global__ void k_prep(const int* __restrict__ deg, float* __restrict__ inv_deg,
                       float* __restrict__ dinv, int* __restrict__ row_start,
                       int* __restrict__ counter) {
    int i = blockIdx.x * TPB + threadIdx.x;
    int lane = threadIdx.x & 63;
    int d = (i < NN) ? deg[i] : 0;
    int incl = d;
    #pragma unroll
    for (int o = 1; o < 64; o <<= 1) {
        int v = __shfl_up(incl, o, 64);
        if (lane >= o) incl += v;
    }
    int total = __shfl(incl, 63, 64);
    int base = 0;
    if (lane == 63) base = atomicAdd(counter, total);
    base = __shfl(base, 63, 64);
    if (i < NN) {
        row_start[i] = base + incl - d;
        inv_deg[i] = d > 0 ? 1.0f / (float)d : 0.0f;
        dinv[i]    = d > 0 ? 1.0f / sqrtf((float)d) : 0.0f;
    }
}

__global__ void k_fill(const int* __restrict__ src, const int* __restrict__ dst,
                       const int* __restrict__ row_start, int* __restrict__ cursor,
                       int* __restrict__ col) {
    int e = blockIdx.x * TPB + threadIdx.x;
    if (e < NE) {
        int d = dst[e];
        int p = atomicAdd(&cursor[d], 1);
        col[row_start[d] + p] = src[e];
    }
}

// ---------------------------------------------------------------- propagation
// mean aggregation, 8 feats: 8 threads/node (epar x half split, 12.5k waves)
__global__ void k_meanprop8(const float* __restrict__ h, const int* __restrict__ row_start,
                            const int* __restrict__ deg, const float* __restrict__ inv_deg,
                            const int* __restrict__ col, float* __restrict__ out) {
    int t = blockIdx.x * TPB + threadIdx.x;
    if (t >= NN * 8) return;
    int n = t >> 3, qd = t & 7;
    int half = qd & 1, epar = qd >> 1;
    int rs = row_start[n], end = rs + deg[n];
    const float4* h4 = (const float4*)h;
    float4 s = make_float4(0,0,0,0);
    int e = rs + epar;
    for (; e + 4 < end; e += 8) {
        int c0 = col[e] * 2 + half, c1 = col[e + 4] * 2 + half;
        float4 a = h4[c0], b = h4[c1];
        s.x += a.x + b.x; s.y += a.y + b.y; s.z += a.z + b.z; s.w += a.w + b.w;
    }
    if (e < end) {
        float4 a = h4[col[e] * 2 + half];
        s.x += a.x; s.y += a.y; s.z += a.z; s.w += a.w;
    }
    #pragma unroll
    for (int o = 2; o < 8; o <<= 1) {
        s.x += __shfl_xor(s.x, o, 64); s.y += __shfl_xor(s.y, o, 64);
        s.z += __shfl_xor(s.z, o, 64); s.w += __shfl_xor(s.w, o, 64);
    }
    if (epar == 0) {
        float w = inv_deg[n];
        ((float4*)out)[n * 2 + half] = make_float4(s.x * w, s.y * w, s.z * w, s.w * w);
    }
}

// mean aggregation, 128 feats, fused transpose: gather with balanced mapping
// (wave = 2 nodes x 32 f4), LDS tile bounce, write a128T[f][n] with coalesced
// 128B row segments. Block = 1024 thr = 32 nodes; NN = 3125*32 exactly.
__global__ __launch_bounds__(1024) void k_meanprop128T(const float* __restrict__ h,
                              const int* __restrict__ row_start,
                              const int* __restrict__ deg, const float* __restrict__ inv_deg,
                              const int* __restrict__ col, float* __restrict__ outT) {
    __shared__ float t[128][33];
    int n0 = blockIdx.x * 32;
    int tid = threadIdx.x;
    int nl = tid >> 5;          // 0..31 node local
    int f4 = tid & 31;          // 0..31 feature quad
    int n = n0 + nl;
    int rs = row_start[n], end = rs + deg[n];
    const float4* h4 = (const float4*)h;
    float4 s = make_float4(0.f, 0.f, 0.f, 0.f);
    int e = rs;
    for (; e + 3 < end; e += 4) {
        float4 v0 = h4[(size_t)col[e] * 32 + f4];
        float4 v1 = h4[(size_t)col[e + 1] * 32 + f4];
        float4 v2 = h4[(size_t)col[e + 2] * 32 + f4];
        float4 v3 = h4[(size_t)col[e + 3] * 32 + f4];
        s.x += (v0.x + v1.x) + (v2.x + v3.x);
        s.y += (v0.y + v1.y) + (v2.y + v3.y);
        s.z += (v0.z + v1.z) + (v2.z + v3.z);
        s.w += (v0.w + v1.w) + (v2.w + v3.w);
    }
    for (; e < end; ++e) {
        float4 v = h4[(size_t)col[e] * 32 + f4];
        s.x += v.x; s.y += v.y; s.z += v.z; s.w += v.w;
    }
    float w = inv_deg[n];
    t[f4 * 4 + 0][nl] = s.x * w;
    t[f4 * 4 + 1][nl] = s.y * w;
    t[f4 * 4 + 2][nl] = s.z * w;
    t[f4 * 4 + 3][nl] = s.w * w;
    __syncthreads();
    int k = tid >> 3;           // 0..127 feature row
    int q = tid & 7;            // 0..7 node quad
    float4 v = make_float4(t[k][q * 4], t[k][q * 4 + 1], t[k][q * 4 + 2], t[k][q * 4 + 3]);
    *(float4*)(outT + (size_t)k * NN + n0 + q * 4) = v;
}

// fused TAG layer-1 step: 8 threads/node
__global__ void k_tagstep(const float* __restrict__ q, const int* __restrict__ row_start,
                          const int* __restrict__ deg, const float* __restrict__ dinv,
                          const int* __restrict__ col, float* __restrict__ qout,
                          const float* __restrict__ Wa, const float* __restrict__ Wb,
                          float* __restrict__ outa, float* __restrict__ outb,
                          const float* __restrict__ ba, const float* __restrict__ bb,
                          int fina, int finb) {
    int t = blockIdx.x * TPB + threadIdx.x;
    if (t >= NN * 8) return;
    int n = t >> 3, qd = t & 7;
    int half = qd & 1, epar = qd >> 1;
    int rs = row_start[n], end = rs + deg[n];
    const float4* q4 = (const float4*)q;
    float4 s = make_float4(0,0,0,0);
    int e = rs + epar;
    for (; e + 4 < end; e += 8) {
        int c0 = col[e] * 2 + half, c1 = col[e + 4] * 2 + half;
        float4 a = q4[c0], b = q4[c1];
        s.x += a.x + b.x; s.y += a.y + b.y; s.z += a.z + b.z; s.w += a.w + b.w;
    }
    if (e < end) {
        float4 a = q4[col[e] * 2 + half];
        s.x += a.x; s.y += a.y; s.z += a.z; s.w += a.w;
    }
    #pragma unroll
    for (int o = 2; o < 8; o <<= 1) {
        s.x += __shfl_xor(s.x, o, 64); s.y += __shfl_xor(s.y, o, 64);
        s.z += __shfl_xor(s.z, o, 64); s.w += __shfl_xor(s.w, o, 64);
    }
    float dn = dinv[n];
    float m0 = s.x * dn, m1 = s.y * dn, m2 = s.z * dn, m3 = s.w * dn;
    if (qout && epar == 0) {
        ((float4*)qout)[n * 2 + half] = make_float4(m0 * dn, m1 * dn, m2 * dn, m3 * dn);
    }
    float o0 = __shfl_xor(m0, 1, 64), o1 = __shfl_xor(m1, 1, 64);
    float o2 = __shfl_xor(m2, 1, 64), o3 = __shfl_xor(m3, 1, 64);
    float h[8];
    if (half) {
        h[0] = o0; h[1] = o1; h[2] = o2; h[3] = o3;
        h[4] = m0; h[5] = m1; h[6] = m2; h[7] = m3;
    } else {
        h[0] = m0; h[1] = m1; h[2] = m2; h[3] = m3;
        h[4] = o0; h[5] = o1; h[6] = o2; h[7] = o3;
    }
    int f = qd;
    if (Wa) {
        float v = outa[(size_t)n * 8 + f];
        #pragma unroll
        for (int j = 0; j < 8; ++j) v += h[j] * Wa[j * 8 + f];
        if (fina) v = fmaxf(v + ba[f], 0.f);
        outa[(size_t)n * 8 + f] = v;
    }
    {
        float v = outb[(size_t)n * 8 + f];
        #pragma unroll
        for (int j = 0; j < 8; ++j) v += h[j] * Wb[j * 8 + f];
        if (finb) v = fmaxf(v + bb[f], 0.f);
        outb[(size_t)n * 8 + f] = v;
    }
}

// scalar sym-prop Horner step, 8 thr/node, q-prescaled input (1 load/edge).
__global__ void k_symprop1n(const float* __restrict__ qin, const float* __restrict__ yk,
                            const int* __restrict__ row_start, const int* __restrict__ deg,
                            const float* __restrict__ dinv, const int* __restrict__ col,
                            float* __restrict__ qout, int qstride) {
    int t = blockIdx.x * TPB + threadIdx.x;
    if (t >= NN * 8) return;
    int n = t >> 3, qd = t & 7;
    int rs = row_start[n], d = deg[n];
    float s = 0.f;
    for (int e = rs + qd; e < rs + d; e += 8) s += qin[col[e]];
    s += __shfl_xor(s, 1, 64);
    s += __shfl_xor(s, 2, 64);
    s += __shfl_xor(s, 4, 64);
    if (qd == 0) {
        float dn = dinv[n];
        qout[(size_t)n * qstride] = dn * (dn * s + yk[n]);
    }
}

// fused 2-channel sym-prop Horner step, 8 thr/node, float2 loads
__global__ void k_symprop2(const float* __restrict__ q2in, const float* __restrict__ yka,
                           const float* __restrict__ ykb, const int* __restrict__ row_start,
                           const int* __restrict__ deg, const float* __restrict__ dinv,
                           const int* __restrict__ col, float* __restrict__ q2out) {
    int t = blockIdx.x * TPB + threadIdx.x;
    if (t >= NN * 8) return;
    int n = t >> 3, qd = t & 7;
    int rs = row_start[n], d = deg[n];
    const float2* q2 = (const float2*)q2in;
    float sa = 0.f, sb = 0.f;
    for (int e = rs + qd; e < rs + d; e += 8) {
        float2 v = q2[col[e]];
        sa += v.x; sb += v.y;
    }
    sa += __shfl_xor(sa, 1, 64); sa += __shfl_xor(sa, 2, 64); sa += __shfl_xor(sa, 4, 64);
    sb += __shfl_xor(sb, 1, 64); sb += __shfl_xor(sb, 2, 64); sb += __shfl_xor(sb, 4, 64);
    if (qd == 0) {
        float dn = dinv[n];
        ((float2*)q2out)[n] = make_float2(dn * (dn * sa + yka[n]),
                                          dn * (dn * sb + ykb[n]));
    }
}

// final 2-channel sym-prop step + full output combine
__global__ void k_symprop2fin(const float* __restrict__ q2in, const float* __restrict__ yka,
                              const float* __restrict__ ykb, const int* __restrict__ row_start,
                              const int* __restrict__ deg, const float* __restrict__ dinv,
                              const int* __restrict__ col,
                              const float* __restrict__ biasa, const float* __restrict__ biasb,
                              const float* __restrict__ x1f,
                              const float* __restrict__ l2w, const float* __restrict__ l2b,
                              const float* __restrict__ l1w, const float* __restrict__ l1b,
                              float* __restrict__ out) {
    int t = blockIdx.x * TPB + threadIdx.x;
    if (t >= NN * 8) return;
    int n = t >> 3, qd = t & 7;
    int rs = row_start[n], d = deg[n];
    const float2* q2 = (const float2*)q2in;
    float sa = 0.f, sb = 0.f;
    for (int e = rs + qd; e < rs + d; e += 8) {
        float2 v = q2[col[e]];
        sa += v.x; sb += v.y;
    }
    sa += __shfl_xor(sa, 1, 64); sa += __shfl_xor(sa, 2, 64); sa += __shfl_xor(sa, 4, 64);
    sb += __shfl_xor(sb, 1, 64); sb += __shfl_xor(sb, 2, 64); sb += __shfl_xor(sb, 4, 64);
    if (qd == 0) {
        float dn = dinv[n];
        float x2 = fmaxf(dn * sa + yka[n] + biasa[0], 0.f);
        float x3 = fmaxf(dn * sb + ykb[n] + biasb[0], 0.f);
        float x23 = fmaxf(x2 * l2w[0] + x3 * l2w[1] + l2b[0], 0.f);
        out[n] = fmaxf(x1f[n] * l1w[0] + x23 * l1w[1] + l1b[0], 0.f);
    }
}

// sum the 8 partial dots from k_sage2f
__global__ void k_red8(const float* __restrict__ ylp, const float* __restrict__ yrp,
                       float* __restrict__ yl, float* __restrict__ yr) {
    int n = blockIdx.x * TPB + threadIdx.x;
    if (n >= NN) return;
    float sl = 0.f, sr = 0.f;
    #pragma unroll
    for (int j = 0; j < 8; ++j) {
        sl += ylp[(size_t)j * NN + n];
        sr += yrp[(size_t)j * NN + n];
    }
    yl[n] = sl;
    yr[n] = sr;
}

// mean scalar propagation + SAGE3 epilogue, 8 thr/node
__global__ void k_sage3(const float* __restrict__ yl, const float* __restrict__ yr,
                        const int* __restrict__ row_start, const int* __restrict__ deg,
                        const float* __restrict__ inv_deg, const int* __restrict__ col,
                        const float* __restrict__ b3, float* __restrict__ x1f) {
    int t = blockIdx.x * TPB + threadIdx.x;
    if (t >= NN * 8) return;
    int n = t >> 3, q = t & 7;
    int rs = row_start[n], d = deg[n];
    float s = 0.f;
    for (int e = rs + q; e < rs + d; e += 8) s += yl[col[e]];
    s += __shfl_xor(s, 1, 64);
    s += __shfl_xor(s, 2, 64);
    s += __shfl_xor(s, 4, 64);
    if (q == 0) x1f[n] = fmaxf(s * inv_deg[n] + yr[n] + b3[0], 0.f);
}

// ---------------------------------------------------------------- dense transforms
// SAGE1: lane = node, og-block from grid.y; writes x1 row-major + x1T transposed
__global__ __launch_bounds__(256) void k_sage1(const float* __restrict__ a8,
                        const float* __restrict__ x,
                        const float* __restrict__ W1l, const float* __restrict__ W1r,
                        const float* __restrict__ b1, float* __restrict__ x1,
                        float* __restrict__ x1T) {
    int n = blockIdx.x * 256 + threadIdx.x;
    int og = blockIdx.y * 8;
    int nc = (n < NN) ? n : (NN - 1);
    float acc[8];
    #pragma unroll
    for (int j = 0; j < 8; ++j) acc[j] = b1[og + j];
    const float* ar = a8 + (size_t)nc * 8;
    const float* xr = x + (size_t)nc * 8;
    #pragma unroll
    for (int k = 0; k < 8; ++k) {
        float av = ar[k], xv = xr[k];
        const float4* wl = (const float4*)(W1l + k * 128 + og);
        const float4* wr = (const float4*)(W1r + k * 128 + og);
        float4 l0 = wl[0], l1 = wl[1], r0 = wr[0], r1 = wr[1];
        acc[0] += av * l0.x + xv * r0.x;
        acc[1] += av * l0.y + xv * r0.y;
        acc[2] += av * l0.z + xv * r0.z;
        acc[3] += av * l0.w + xv * r0.w;
        acc[4] += av * l1.x + xv * r1.x;
        acc[5] += av * l1.y + xv * r1.y;
        acc[6] += av * l1.z + xv * r1.z;
        acc[7] += av * l1.w + xv * r1.w;
    }
    if (n < NN) {
        #pragma unroll
        for (int j = 0; j < 8; ++j) acc[j] = fmaxf(acc[j], 0.f);
        *(float4*)(x1 + (size_t)n * 128 + og)     = make_float4(acc[0], acc[1], acc[2], acc[3]);
        *(float4*)(x1 + (size_t)n * 128 + og + 4) = make_float4(acc[4], acc[5], acc[6], acc[7]);
        #pragma unroll
        for (int j = 0; j < 8; ++j)
            x1T[(size_t)(og + j) * NN + n] = acc[j];
    }
}

// SAGE2 fused with SAGE3 pre-multiply: R8 geometry verbatim (og-eighths,
// acc[16], unroll 4, 3136 blocks = 12.3k waves, XCD swizzle) — measured best.
__global__ __launch_bounds__(256) void k_sage2f(const float* __restrict__ aT,
        const float* __restrict__ xT, const float* __restrict__ W2l,
        const float* __restrict__ W2r, const float* __restrict__ b2,
        const float* __restrict__ W3l, const float* __restrict__ W3r,
        float* __restrict__ ylp, float* __restrict__ yrp) {
    int xcd = blockIdx.x & 7;
    int s = blockIdx.x >> 3;            // 0..391
    int xblk = xcd * 49 + (s >> 3);     // 0..391 (392 node-blocks)
    int ogq = s & 7;
    int og = ogq * 16;
    int n0 = xblk * 256 + threadIdx.x;
    int n = (n0 < NN) ? n0 : (NN - 1);
    float acc[16];
    #pragma unroll
    for (int j = 0; j < 16; ++j) acc[j] = b2[og + j];
    const float* ap = aT + n;
    const float* xp = xT + n;
    const float* wlp = W2l + og;
    const float* wrp = W2r + og;
    #pragma unroll 4
    for (int k = 0; k < 128; ++k) {
        float a = ap[0], xv = xp[0];
        ap += NN; xp += NN;
        const float4* wl4 = (const float4*)(wlp + (k << 7));
        const float4* wr4 = (const float4*)(wrp + (k << 7));
        #pragma unroll
        for (int q = 0; q < 4; ++q) {
            float4 wl = wl4[q], wr = wr4[q];
            acc[q * 4 + 0] += a * wl.x + xv * wr.x;
            acc[q * 4 + 1] += a * wl.y + xv * wr.y;
            acc[q * 4 + 2] += a * wl.z + xv * wr.z;
            acc[q * 4 + 3] += a * wl.w + xv * wr.w;
        }
    }
    float pl = 0.f, pr = 0.f;
    #pragma unroll
    for (int j = 0; j < 16; ++j) {
        float v = fmaxf(acc[j], 0.f);
        pl += v * W3l[og + j];
        pr += v * W3r[og + j];
    }
    if (n0 < NN) {
        ylp[(size_t)ogq * NN + n0] = pl;
        yrp[(size_t)ogq * NN + n0] = pr;
    }
}

// TAG k=0 term for both branches + q0 = dinv[n]*x[n]
__global__ void k_taginit(const float* __restrict__ x, const float* __restrict__ TaW,
                          const float* __restrict__ TbW, const float* __restrict__ dinv,
                          float* __restrict__ outa, float* __restrict__ outb,
                          float* __restrict__ q0) {
    int t = blockIdx.x * TPB + threadIdx.x;
    if (t >= NN * 8) return;
    int n = t >> 3, o = t & 7;
    const float* xr = x + (size_t)n * 8;
    float sa = 0.f, sb = 0.f;
    #pragma unroll
    for (int j = 0; j < 8; ++j) {
        float v = xr[j];
        sa += v * TaW[j * 8 + o];
        sb += v * TbW[j * 8 + o];
    }
    outa[t] = sa;
    outb[t] = sb;
    q0[t] = xr[o] * dinv[n];
}

// both TAG layer-2 projections in one kernel; last k of each chain pre-scaled
__global__ void k_tag2projAB(const float* __restrict__ outa, const float* __restrict__ outb,
                             const float* __restrict__ TaW2, const float* __restrict__ TbW2,
                             float* __restrict__ ya, float* __restrict__ yb,
                             const float* __restrict__ dinv,
                             float* __restrict__ q2a, float* __restrict__ qb0) {
    int n = blockIdx.x * TPB + threadIdx.x;
    if (n >= NN) return;
    float dn = dinv[n];
    float ha[8], hb[8];
    #pragma unroll
    for (int j = 0; j < 8; ++j) ha[j] = outa[(size_t)n * 8 + j];
    #pragma unroll
    for (int j = 0; j < 8; ++j) hb[j] = outb[(size_t)n * 8 + j];
    #pragma unroll
    for (int k = 0; k < 4; ++k) {
        float s = 0.f;
        #pragma unroll
        for (int j = 0; j < 8; ++j) s += ha[j] * TaW2[k * 8 + j];
        if (k == 3) q2a[(size_t)n * 2] = s * dn;
        else        ya[(size_t)k * NN + n] = s;
    }
    #pragma unroll
    for (int k = 0; k < 10; ++k) {
        float s = 0.f;
        #pragma unroll
        for (int j = 0; j < 8; ++j) s += hb[j] * TbW2[k * 8 + j];
        if (k == 9) qb0[n] = s * dn;
        else        yb[(size_t)k * NN + n] = s;
    }
}

// ---------------------------------------------------------------- host launch
#define GL(kern, n, ...) \
    kern<<<dim3((unsigned)(((long)(n) + TPB - 1) / TPB)), dim3(TPB), 0, stream>>>(__VA_ARGS__)

extern "C" void kernel_launch(void* const* d_in, const int* in_sizes, int n_in,
                              void* d_out, int out_size, void* d_ws, size_t ws_size,
                              hipStream_t stream) {
    (void)in_sizes; (void)n_in; (void)out_size; (void)ws_size;
    const float* x   = (const float*)d_in[0];
    const int*   ei  = (const int*)d_in[1];
    const int*   src = ei;
    const int*   dst = ei + NE;
    const float* W1l = (const float*)d_in[2];
    const float* W1r = (const float*)d_in[3];
    const float* b1  = (const float*)d_in[4];
    const float* W2l = (const float*)d_in[5];
    const float* W2r = (const float*)d_in[6];
    const float* b2  = (const float*)d_in[7];
    const float* W3l = (const float*)d_in[8];
    const float* W3r = (const float*)d_in[9];
    const float* b3  = (const float*)d_in[10];
    const float* TaW1 = (const float*)d_in[11];
    const float* TaB1 = (const float*)d_in[12];
    const float* TaW2 = (const float*)d_in[13];
    const float* TaB2 = (const float*)d_in[14];
    const float* TbW1 = (const float*)d_in[15];
    const float* TbB1 = (const float*)d_in[16];
    const float* TbW2 = (const float*)d_in[17];
    const float* TbB2 = (const float*)d_in[18];
    const float* l2w = (const float*)d_in[19];
    const float* l2b = (const float*)d_in[20];
    const float* l1w = (const float*)d_in[21];
    const float* l1b = (const float*)d_in[22];
    float* out = (float*)d_out;

    char* p = (char*)d_ws;
    size_t off = 0;
    auto alloc = [&](size_t bytes) -> void* {
        void* r = p + off;
        off = (off + bytes + 255) & ~(size_t)255;
        return r;
    };
    int*   deg       = (int*)  alloc((size_t)NN * 4);
    float* inv_deg   = (float*)alloc((size_t)NN * 4);
    float* dinv      = (float*)alloc((size_t)NN * 4);
    int*   row_start = (int*)  alloc((size_t)NN * 4);
    int*   cursor    = (int*)  alloc((size_t)NN * 4);
    int*   counter   = (int*)  alloc(256);
    int*   col       = (int*)  alloc((size_t)NE * 4);
    float* a8        = (float*)alloc((size_t)NN * 8 * 4);
    float* qA        = (float*)alloc((size_t)NN * 8 * 4);
    float* qB        = (float*)alloc((size_t)NN * 8 * 4);
    float* outa      = (float*)alloc((size_t)NN * 8 * 4);
    float* outb      = (float*)alloc((size_t)NN * 8 * 4);
    float* x1        = (float*)alloc((size_t)NN * 128 * 4);
    float* a128T     = (float*)alloc((size_t)NN * 128 * 4);
    float* x1T       = (float*)alloc((size_t)NN * 128 * 4);
    float* ylp       = (float*)alloc((size_t)NN * 8 * 4);
    float* yrp       = (float*)alloc((size_t)NN * 8 * 4);
    float* yl        = (float*)alloc((size_t)NN * 4);
    float* yr        = (float*)alloc((size_t)NN * 4);
    float* x1f       = (float*)alloc((size_t)NN * 4);
    float* x2s       = (float*)alloc((size_t)NN * 4);
    float* tA        = (float*)alloc((size_t)NN * 4);
    float* tB        = (float*)alloc((size_t)NN * 4);
    float* qb0       = (float*)alloc((size_t)NN * 4);
    float* q2a       = (float*)alloc((size_t)NN * 8);
    float* q2b       = (float*)alloc((size_t)NN * 8);
    float* ya        = (float*)alloc((size_t)NN * 4 * 4);
    float* yb        = (float*)alloc((size_t)NN * 10 * 4);

    // CSR build (reused by all edge passes)
    GL(k_init, NN, deg, cursor, counter);
    GL(k_deg, NE, dst, deg);
    GL(k_prep, NN, deg, inv_deg, dinv, row_start, counter);
    GL(k_fill, NE, src, dst, row_start, cursor, col);

    // SAGE1 (writes x1 row-major + x1T transposed directly)
    GL(k_meanprop8, (long)NN * 8, x, row_start, deg, inv_deg, col, a8);
    k_sage1<<<dim3((NN + 255) / 256, 16), dim3(256), 0, stream>>>(a8, x, W1l, W1r, b1, x1, x1T);
    // SAGE2+SAGE3-premul: fused aggregate+transpose, then fused GEMM+dot
    k_meanprop128T<<<dim3(NN / 32), dim3(1024), 0, stream>>>(x1, row_start, deg, inv_deg, col, a128T);
    k_sage2f<<<dim3(3136), dim3(256), 0, stream>>>(a128T, x1T, W2l, W2r, b2, W3l, W3r, ylp, yrp);
    GL(k_red8, NN, ylp, yrp, yl, yr);
    // SAGE3 scalar propagation
    GL(k_sage3, (long)NN * 8, yl, yr, row_start, deg, inv_deg, col, b3, x1f);

    // TAG layer 1 — shared P^k x chain, q-prescaled, fused projections
    GL(k_taginit, (long)NN * 8, x, TaW1, TbW1, dinv, outa, outb, qA);
    {
        float* qcur = qA;
        float* qnext = qB;
        for (int k = 1; k <= 9; ++k) {
            float* qout = (k < 9) ? qnext : nullptr;
            const float* Wa = (k <= 3) ? (TaW1 + (size_t)k * 64) : nullptr;
            GL(k_tagstep, (long)NN * 8, qcur, row_start, deg, dinv, col, qout,
               Wa, TbW1 + (size_t)k * 64, outa, outb, TaB1, TbB1,
               (k == 3) ? 1 : 0, (k == 9) ? 1 : 0);
            if (qout) { float* tmp = qcur; qcur = qnext; qnext = tmp; }
        }
    }

    // TAG layer 2 projections (both branches, one kernel)
    GL(k_tag2projAB, NN, outa, outb, TaW2, TbW2, ya, yb, dinv, q2a, qb0);

    // TAGb solo Horner steps 1..6; step 6 lands in q2a[2n+1]
    GL(k_symprop1n, (long)NN * 8, qb0, yb + 8 * NN, row_start, deg, dinv, col, tA, 1);
    GL(k_symprop1n, (long)NN * 8, tA,  yb + 7 * NN, row_start, deg, dinv, col, tB, 1);
    GL(k_symprop1n, (long)NN * 8, tB,  yb + 6 * NN, row_start, deg, dinv, col, tA, 1);
    GL(k_symprop1n, (long)NN * 8, tA,  yb + 5 * NN, row_start, deg, dinv, col, tB, 1);
    GL(k_symprop1n, (long)NN * 8, tB,  yb + 4 * NN, row_start, deg, dinv, col, tA, 1);
    GL(k_symprop1n, (long)NN * 8, tA,  yb + 3 * NN, row_start, deg, dinv, col, q2a + 1, 2);

    // fused a+b Horner steps (float2): q2a -> q2b -> q2a -> final combine
    GL(k_symprop2, (long)NN * 8, q2a, ya + 2 * NN, yb + 2 * NN, row_start, deg, dinv, col, q2b);
    GL(k_symprop2, (long)NN * 8, q2b, ya + 1 * NN, yb + 1 * NN, row_start, deg, dinv, col, q2a);
    GL(k_symprop2fin, (long)NN * 8, q2a, ya + 0 * NN, yb + 0 * NN, row_start, deg, dinv, col,
       TaB2, TbB2, x1f, l2w, l2b, l1w, l1b, out);
}

// Round 16
// 730.103 us; speedup vs baseline: 1.4129x; 1.0163x over previous
//
#include <hip/hip_runtime.h>

#define NN 100000
#define NE 1600000
#define TPB 256

// ---------------------------------------------------------------- CSR build
__global__ void k_init(int* __restrict__ deg, int* __restrict__ cursor, int* __restrict__ counter) {
    int i = blockIdx.x * TPB + threadIdx.x;
    if (i < NN) { deg[i] = 0; cursor[i] = 0; }
    if (i == 0) counter[0] = 0;
}

__global__ void k_deg(const int* __restrict__ dst, int* __restrict__ deg) {
    int e = blockIdx.x * TPB + threadIdx.x;
    if (e < NE) atomicAdd(&deg[dst[e]], 1);
}

// wave64 scan: one atomic per WAVE on the global counter
__global__ void k_prep(const int* __restrict__ deg, float* __restrict__ inv_deg,
                       float* __restrict__ dinv, int* __restrict__ row_start,
                       int* __restrict__ counter) {
    int i = blockIdx.x * TPB + threadIdx.x;
    int lane = threadIdx.x & 63;
    int d = (i < NN) ? deg[i] : 0;
    int incl = d;
    #pragma unroll
    for (int o = 1; o < 64; o <<= 1) {
        int v = __shfl_up(incl, o, 64);
        if (lane >= o) incl += v;
    }
    int total = __shfl(incl, 63, 64);
    int base = 0;
    if (lane == 63) base = atomicAdd(counter, total);
    base = __shfl(base, 63, 64);
    if (i < NN) {
        row_start[i] = base + incl - d;
        inv_deg[i] = d > 0 ? 1.0f / (float)d : 0.0f;
        dinv[i]    = d > 0 ? 1.0f / sqrtf((float)d) : 0.0f;
    }
}

__global__ void k_fill(const int* __restrict__ src, const int* __restrict__ dst,
                       const int* __restrict__ row_start, int* __restrict__ cursor,
                       int* __restrict__ col) {
    int e = blockIdx.x * TPB + threadIdx.x;
    if (e < NE) {
        int d = dst[e];
        int p = atomicAdd(&cursor[d], 1);
        col[row_start[d] + p] = src[e];
    }
}

// ---------------------------------------------------------------- propagation
// mean aggregation, 8 feats: 2 threads per node, float4 gathers, shfl combine
__global__ void k_meanprop8(const float* __restrict__ h, const int* __restrict__ row_start,
                            const int* __restrict__ deg, const float* __restrict__ inv_deg,
                            const int* __restrict__ col, float* __restrict__ out) {
    int t = blockIdx.x * TPB + threadIdx.x;
    if (t >= NN * 2) return;
    int n = t >> 1, half = t & 1;
    int rs = row_start[n], end = rs + deg[n];
    const float4* h4 = (const float4*)h;
    float4 s0 = make_float4(0,0,0,0), s1 = make_float4(0,0,0,0);
    int e = rs + half;
    for (; e + 2 < end; e += 4) {
        int c0 = col[e] * 2, c1 = col[e + 2] * 2;
        float4 a0 = h4[c0], a1 = h4[c0 + 1], b0 = h4[c1], b1 = h4[c1 + 1];
        s0.x += a0.x + b0.x; s0.y += a0.y + b0.y; s0.z += a0.z + b0.z; s0.w += a0.w + b0.w;
        s1.x += a1.x + b1.x; s1.y += a1.y + b1.y; s1.z += a1.z + b1.z; s1.w += a1.w + b1.w;
    }
    if (e < end) {
        int c0 = col[e] * 2;
        float4 a0 = h4[c0], a1 = h4[c0 + 1];
        s0.x += a0.x; s0.y += a0.y; s0.z += a0.z; s0.w += a0.w;
        s1.x += a1.x; s1.y += a1.y; s1.z += a1.z; s1.w += a1.w;
    }
    s0.x += __shfl_xor(s0.x, 1, 64); s0.y += __shfl_xor(s0.y, 1, 64);
    s0.z += __shfl_xor(s0.z, 1, 64); s0.w += __shfl_xor(s0.w, 1, 64);
    s1.x += __shfl_xor(s1.x, 1, 64); s1.y += __shfl_xor(s1.y, 1, 64);
    s1.z += __shfl_xor(s1.z, 1, 64); s1.w += __shfl_xor(s1.w, 1, 64);
    float w = inv_deg[n];
    float4 o = (half == 0) ? s0 : s1;
    o.x *= w; o.y *= w; o.z *= w; o.w *= w;
    ((float4*)out)[n * 2 + half] = o;
}

// mean aggregation, 128 feats, fused transpose: gather with balanced mapping
// (wave = 2 nodes x 32 f4), LDS tile bounce, write a128T[f][n] with coalesced
// 128B row segments. Block = 1024 thr = 32 nodes; NN = 3125*32 exactly.
__global__ __launch_bounds__(1024) void k_meanprop128T(const float* __restrict__ h,
                              const int* __restrict__ row_start,
                              const int* __restrict__ deg, const float* __restrict__ inv_deg,
                              const int* __restrict__ col, float* __restrict__ outT) {
    __shared__ float t[128][33];
    int n0 = blockIdx.x * 32;
    int tid = threadIdx.x;
    int nl = tid >> 5;          // 0..31 node local
    int f4 = tid & 31;          // 0..31 feature quad
    int n = n0 + nl;
    int rs = row_start[n], end = rs + deg[n];
    const float4* h4 = (const float4*)h;
    float4 s = make_float4(0.f, 0.f, 0.f, 0.f);
    int e = rs;
    for (; e + 3 < end; e += 4) {
        float4 v0 = h4[(size_t)col[e] * 32 + f4];
        float4 v1 = h4[(size_t)col[e + 1] * 32 + f4];
        float4 v2 = h4[(size_t)col[e + 2] * 32 + f4];
        float4 v3 = h4[(size_t)col[e + 3] * 32 + f4];
        s.x += (v0.x + v1.x) + (v2.x + v3.x);
        s.y += (v0.y + v1.y) + (v2.y + v3.y);
        s.z += (v0.z + v1.z) + (v2.z + v3.z);
        s.w += (v0.w + v1.w) + (v2.w + v3.w);
    }
    for (; e < end; ++e) {
        float4 v = h4[(size_t)col[e] * 32 + f4];
        s.x += v.x; s.y += v.y; s.z += v.z; s.w += v.w;
    }
    float w = inv_deg[n];
    t[f4 * 4 + 0][nl] = s.x * w;
    t[f4 * 4 + 1][nl] = s.y * w;
    t[f4 * 4 + 2][nl] = s.z * w;
    t[f4 * 4 + 3][nl] = s.w * w;
    __syncthreads();
    int k = tid >> 3;           // 0..127 feature row
    int q = tid & 7;            // 0..7 node quad
    float4 v = make_float4(t[k][q * 4], t[k][q * 4 + 1], t[k][q * 4 + 2], t[k][q * 4 + 3]);
    *(float4*)(outT + (size_t)k * NN + n0 + q * 4) = v;
}

// fused TAG layer-1 step: 8 threads/node
__global__ void k_tagstep(const float* __restrict__ q, const int* __restrict__ row_start,
                          const int* __restrict__ deg, const float* __restrict__ dinv,
                          const int* __restrict__ col, float* __restrict__ qout,
                          const float* __restrict__ Wa, const float* __restrict__ Wb,
                          float* __restrict__ outa, float* __restrict__ outb,
                          const float* __restrict__ ba, const float* __restrict__ bb,
                          int fina, int finb) {
    int t = blockIdx.x * TPB + threadIdx.x;
    if (t >= NN * 8) return;
    int n = t >> 3, qd = t & 7;
    int half = qd & 1, epar = qd >> 1;
    int rs = row_start[n], end = rs + deg[n];
    const float4* q4 = (const float4*)q;
    float4 s = make_float4(0,0,0,0);
    int e = rs + epar;
    for (; e + 4 < end; e += 8) {
        int c0 = col[e] * 2 + half, c1 = col[e + 4] * 2 + half;
        float4 a = q4[c0], b = q4[c1];
        s.x += a.x + b.x; s.y += a.y + b.y; s.z += a.z + b.z; s.w += a.w + b.w;
    }
    if (e < end) {
        float4 a = q4[col[e] * 2 + half];
        s.x += a.x; s.y += a.y; s.z += a.z; s.w += a.w;
    }
    #pragma unroll
    for (int o = 2; o < 8; o <<= 1) {
        s.x += __shfl_xor(s.x, o, 64); s.y += __shfl_xor(s.y, o, 64);
        s.z += __shfl_xor(s.z, o, 64); s.w += __shfl_xor(s.w, o, 64);
    }
    float dn = dinv[n];
    float m0 = s.x * dn, m1 = s.y * dn, m2 = s.z * dn, m3 = s.w * dn;
    if (qout && epar == 0) {
        ((float4*)qout)[n * 2 + half] = make_float4(m0 * dn, m1 * dn, m2 * dn, m3 * dn);
    }
    float o0 = __shfl_xor(m0, 1, 64), o1 = __shfl_xor(m1, 1, 64);
    float o2 = __shfl_xor(m2, 1, 64), o3 = __shfl_xor(m3, 1, 64);
    float h[8];
    if (half) {
        h[0] = o0; h[1] = o1; h[2] = o2; h[3] = o3;
        h[4] = m0; h[5] = m1; h[6] = m2; h[7] = m3;
    } else {
        h[0] = m0; h[1] = m1; h[2] = m2; h[3] = m3;
        h[4] = o0; h[5] = o1; h[6] = o2; h[7] = o3;
    }
    int f = qd;
    if (Wa) {
        float v = outa[(size_t)n * 8 + f];
        #pragma unroll
        for (int j = 0; j < 8; ++j) v += h[j] * Wa[j * 8 + f];
        if (fina) v = fmaxf(v + ba[f], 0.f);
        outa[(size_t)n * 8 + f] = v;
    }
    {
        float v = outb[(size_t)n * 8 + f];
        #pragma unroll
        for (int j = 0; j < 8; ++j) v += h[j] * Wb[j * 8 + f];
        if (finb) v = fmaxf(v + bb[f], 0.f);
        outb[(size_t)n * 8 + f] = v;
    }
}

// scalar sym-prop Horner step, 8 thr/node, q-prescaled input (1 load/edge).
__global__ void k_symprop1n(const float* __restrict__ qin, const float* __restrict__ yk,
                            const int* __restrict__ row_start, const int* __restrict__ deg,
                            const float* __restrict__ dinv, const int* __restrict__ col,
                            float* __restrict__ qout, int qstride) {
    int t = blockIdx.x * TPB + threadIdx.x;
    if (t >= NN * 8) return;
    int n = t >> 3, qd = t & 7;
    int rs = row_start[n], d = deg[n];
    float s = 0.f;
    for (int e = rs + qd; e < rs + d; e += 8) s += qin[col[e]];
    s += __shfl_xor(s, 1, 64);
    s += __shfl_xor(s, 2, 64);
    s += __shfl_xor(s, 4, 64);
    if (qd == 0) {
        float dn = dinv[n];
        qout[(size_t)n * qstride] = dn * (dn * s + yk[n]);
    }
}

// fused 2-channel sym-prop Horner step, 8 thr/node, float2 loads
__global__ void k_symprop2(const float* __restrict__ q2in, const float* __restrict__ yka,
                           const float* __restrict__ ykb, const int* __restrict__ row_start,
                           const int* __restrict__ deg, const float* __restrict__ dinv,
                           const int* __restrict__ col, float* __restrict__ q2out) {
    int t = blockIdx.x * TPB + threadIdx.x;
    if (t >= NN * 8) return;
    int n = t >> 3, qd = t & 7;
    int rs = row_start[n], d = deg[n];
    const float2* q2 = (const float2*)q2in;
    float sa = 0.f, sb = 0.f;
    for (int e = rs + qd; e < rs + d; e += 8) {
        float2 v = q2[col[e]];
        sa += v.x; sb += v.y;
    }
    sa += __shfl_xor(sa, 1, 64); sa += __shfl_xor(sa, 2, 64); sa += __shfl_xor(sa, 4, 64);
    sb += __shfl_xor(sb, 1, 64); sb += __shfl_xor(sb, 2, 64); sb += __shfl_xor(sb, 4, 64);
    if (qd == 0) {
        float dn = dinv[n];
        ((float2*)q2out)[n] = make_float2(dn * (dn * sa + yka[n]),
                                          dn * (dn * sb + ykb[n]));
    }
}

// final 2-channel sym-prop step + full output combine
__global__ void k_symprop2fin(const float* __restrict__ q2in, const float* __restrict__ yka,
                              const float* __restrict__ ykb, const int* __restrict__ row_start,
                              const int* __restrict__ deg, const float* __restrict__ dinv,
                              const int* __restrict__ col,
                              const float* __restrict__ biasa, const float* __restrict__ biasb,
                              const float* __restrict__ x1f,
                              const float* __restrict__ l2w, const float* __restrict__ l2b,
                              const float* __restrict__ l1w, const float* __restrict__ l1b,
                              float* __restrict__ out) {
    int t = blockIdx.x * TPB + threadIdx.x;
    if (t >= NN * 8) return;
    int n = t >> 3, qd = t & 7;
    int rs = row_start[n], d = deg[n];
    const float2* q2 = (const float2*)q2in;
    float sa = 0.f, sb = 0.f;
    for (int e = rs + qd; e < rs + d; e += 8) {
        float2 v = q2[col[e]];
        sa += v.x; sb += v.y;
    }
    sa += __shfl_xor(sa, 1, 64); sa += __shfl_xor(sa, 2, 64); sa += __shfl_xor(sa, 4, 64);
    sb += __shfl_xor(sb, 1, 64); sb += __shfl_xor(sb, 2, 64); sb += __shfl_xor(sb, 4, 64);
    if (qd == 0) {
        float dn = dinv[n];
        float x2 = fmaxf(dn * sa + yka[n] + biasa[0], 0.f);
        float x3 = fmaxf(dn * sb + ykb[n] + biasb[0], 0.f);
        float x23 = fmaxf(x2 * l2w[0] + x3 * l2w[1] + l2b[0], 0.f);
        out[n] = fmaxf(x1f[n] * l1w[0] + x23 * l1w[1] + l1b[0], 0.f);
    }
}

// sum the 8 partial dots from k_sage2f
__global__ void k_red8(const float* __restrict__ ylp, const float* __restrict__ yrp,
                       float* __restrict__ yl, float* __restrict__ yr) {
    int n = blockIdx.x * TPB + threadIdx.x;
    if (n >= NN) return;
    float sl = 0.f, sr = 0.f;
    #pragma unroll
    for (int j = 0; j < 8; ++j) {
        sl += ylp[(size_t)j * NN + n];
        sr += yrp[(size_t)j * NN + n];
    }
    yl[n] = sl;
    yr[n] = sr;
}

// mean scalar propagation + SAGE3 epilogue, 8 thr/node
__global__ void k_sage3(const float* __restrict__ yl, const float* __restrict__ yr,
                        const int* __restrict__ row_start, const int* __restrict__ deg,
                        const float* __restrict__ inv_deg, const int* __restrict__ col,
                        const float* __restrict__ b3, float* __restrict__ x1f) {
    int t = blockIdx.x * TPB + threadIdx.x;
    if (t >= NN * 8) return;
    int n = t >> 3, q = t & 7;
    int rs = row_start[n], d = deg[n];
    float s = 0.f;
    for (int e = rs + q; e < rs + d; e += 8) s += yl[col[e]];
    s += __shfl_xor(s, 1, 64);
    s += __shfl_xor(s, 2, 64);
    s += __shfl_xor(s, 4, 64);
    if (q == 0) x1f[n] = fmaxf(s * inv_deg[n] + yr[n] + b3[0], 0.f);
}

// ---------------------------------------------------------------- dense transforms
// SAGE1: lane = node, og-block from grid.y; writes x1 row-major + x1T transposed
__global__ __launch_bounds__(256) void k_sage1(const float* __restrict__ a8,
                        const float* __restrict__ x,
                        const float* __restrict__ W1l, const float* __restrict__ W1r,
                        const float* __restrict__ b1, float* __restrict__ x1,
                        float* __restrict__ x1T) {
    int n = blockIdx.x * 256 + threadIdx.x;
    int og = blockIdx.y * 8;
    int nc = (n < NN) ? n : (NN - 1);
    float acc[8];
    #pragma unroll
    for (int j = 0; j < 8; ++j) acc[j] = b1[og + j];
    const float* ar = a8 + (size_t)nc * 8;
    const float* xr = x + (size_t)nc * 8;
    #pragma unroll
    for (int k = 0; k < 8; ++k) {
        float av = ar[k], xv = xr[k];
        const float4* wl = (const float4*)(W1l + k * 128 + og);
        const float4* wr = (const float4*)(W1r + k * 128 + og);
        float4 l0 = wl[0], l1 = wl[1], r0 = wr[0], r1 = wr[1];
        acc[0] += av * l0.x + xv * r0.x;
        acc[1] += av * l0.y + xv * r0.y;
        acc[2] += av * l0.z + xv * r0.z;
        acc[3] += av * l0.w + xv * r0.w;
        acc[4] += av * l1.x + xv * r1.x;
        acc[5] += av * l1.y + xv * r1.y;
        acc[6] += av * l1.z + xv * r1.z;
        acc[7] += av * l1.w + xv * r1.w;
    }
    if (n < NN) {
        #pragma unroll
        for (int j = 0; j < 8; ++j) acc[j] = fmaxf(acc[j], 0.f);
        *(float4*)(x1 + (size_t)n * 128 + og)     = make_float4(acc[0], acc[1], acc[2], acc[3]);
        *(float4*)(x1 + (size_t)n * 128 + og + 4) = make_float4(acc[4], acc[5], acc[6], acc[7]);
        #pragma unroll
        for (int j = 0; j < 8; ++j)
            x1T[(size_t)(og + j) * NN + n] = acc[j];
    }
}

// SAGE2 fused with SAGE3 pre-multiply: R8 geometry (og-eighths, acc[16],
// 3136 blocks, XCD swizzle) + explicit 4-deep activation prefetch pipeline:
// next k-group's 8 loads issue before the current group's 64 FMAs, making
// load->use distance ~256 cy (covers ~200 cy L2 latency). Static indexing.
__global__ __launch_bounds__(256) void k_sage2f(const float* __restrict__ aT,
        const float* __restrict__ xT, const float* __restrict__ W2l,
        const float* __restrict__ W2r, const float* __restrict__ b2,
        const float* __restrict__ W3l, const float* __restrict__ W3r,
        float* __restrict__ ylp, float* __restrict__ yrp) {
    int xcd = blockIdx.x & 7;
    int s = blockIdx.x >> 3;            // 0..391
    int xblk = xcd * 49 + (s >> 3);     // 0..391 (392 node-blocks)
    int ogq = s & 7;
    int og = ogq * 16;
    int n0 = xblk * 256 + threadIdx.x;
    int n = (n0 < NN) ? n0 : (NN - 1);
    float acc[16];
    #pragma unroll
    for (int j = 0; j < 16; ++j) acc[j] = b2[og + j];
    const float* ap = aT + n;
    const float* xp = xT + n;
    const float* wlp = W2l + og;
    const float* wrp = W2r + og;
    float an[4], xn[4];
    #pragma unroll
    for (int i = 0; i < 4; ++i) {
        an[i] = ap[0]; xn[i] = xp[0];
        ap += NN; xp += NN;
    }
    for (int k = 0; k < 128; k += 4) {
        float ac[4], xc[4];
        #pragma unroll
        for (int i = 0; i < 4; ++i) { ac[i] = an[i]; xc[i] = xn[i]; }
        if (k + 4 < 128) {
            #pragma unroll
            for (int i = 0; i < 4; ++i) {
                an[i] = ap[0]; xn[i] = xp[0];
                ap += NN; xp += NN;
            }
        }
        #pragma unroll
        for (int i = 0; i < 4; ++i) {
            const float4* wl4 = (const float4*)(wlp + ((k + i) << 7));
            const float4* wr4 = (const float4*)(wrp + ((k + i) << 7));
            float a = ac[i], xv = xc[i];
            #pragma unroll
            for (int q = 0; q < 4; ++q) {
                float4 wl = wl4[q], wr = wr4[q];
                acc[q * 4 + 0] += a * wl.x + xv * wr.x;
                acc[q * 4 + 1] += a * wl.y + xv * wr.y;
                acc[q * 4 + 2] += a * wl.z + xv * wr.z;
                acc[q * 4 + 3] += a * wl.w + xv * wr.w;
            }
        }
    }
    float pl = 0.f, pr = 0.f;
    #pragma unroll
    for (int j = 0; j < 16; ++j) {
        float v = fmaxf(acc[j], 0.f);
        pl += v * W3l[og + j];
        pr += v * W3r[og + j];
    }
    if (n0 < NN) {
        ylp[(size_t)ogq * NN + n0] = pl;
        yrp[(size_t)ogq * NN + n0] = pr;
    }
}

// TAG k=0 term for both branches + q0 = dinv[n]*x[n]
__global__ void k_taginit(const float* __restrict__ x, const float* __restrict__ TaW,
                          const float* __restrict__ TbW, const float* __restrict__ dinv,
                          float* __restrict__ outa, float* __restrict__ outb,
                          float* __restrict__ q0) {
    int t = blockIdx.x * TPB + threadIdx.x;
    if (t >= NN * 8) return;
    int n = t >> 3, o = t & 7;
    const float* xr = x + (size_t)n * 8;
    float sa = 0.f, sb = 0.f;
    #pragma unroll
    for (int j = 0; j < 8; ++j) {
        float v = xr[j];
        sa += v * TaW[j * 8 + o];
        sb += v * TbW[j * 8 + o];
    }
    outa[t] = sa;
    outb[t] = sb;
    q0[t] = xr[o] * dinv[n];
}

// both TAG layer-2 projections in one kernel; last k of each chain pre-scaled
__global__ void k_tag2projAB(const float* __restrict__ outa, const float* __restrict__ outb,
                             const float* __restrict__ TaW2, const float* __restrict__ TbW2,
                             float* __restrict__ ya, float* __restrict__ yb,
                             const float* __restrict__ dinv,
                             float* __restrict__ q2a, float* __restrict__ qb0) {
    int n = blockIdx.x * TPB + threadIdx.x;
    if (n >= NN) return;
    float dn = dinv[n];
    float ha[8], hb[8];
    #pragma unroll
    for (int j = 0; j < 8; ++j) ha[j] = outa[(size_t)n * 8 + j];
    #pragma unroll
    for (int j = 0; j < 8; ++j) hb[j] = outb[(size_t)n * 8 + j];
    #pragma unroll
    for (int k = 0; k < 4; ++k) {
        float s = 0.f;
        #pragma unroll
        for (int j = 0; j < 8; ++j) s += ha[j] * TaW2[k * 8 + j];
        if (k == 3) q2a[(size_t)n * 2] = s * dn;
        else        ya[(size_t)k * NN + n] = s;
    }
    #pragma unroll
    for (int k = 0; k < 10; ++k) {
        float s = 0.f;
        #pragma unroll
        for (int j = 0; j < 8; ++j) s += hb[j] * TbW2[k * 8 + j];
        if (k == 9) qb0[n] = s * dn;
        else        yb[(size_t)k * NN + n] = s;
    }
}

// ---------------------------------------------------------------- host launch
#define GL(kern, n, ...) \
    kern<<<dim3((unsigned)(((long)(n) + TPB - 1) / TPB)), dim3(TPB), 0, stream>>>(__VA_ARGS__)

extern "C" void kernel_launch(void* const* d_in, const int* in_sizes, int n_in,
                              void* d_out, int out_size, void* d_ws, size_t ws_size,
                              hipStream_t stream) {
    (void)in_sizes; (void)n_in; (void)out_size; (void)ws_size;
    const float* x   = (const float*)d_in[0];
    const int*   ei  = (const int*)d_in[1];
    const int*   src = ei;
    const int*   dst = ei + NE;
    const float* W1l = (const float*)d_in[2];
    const float* W1r = (const float*)d_in[3];
    const float* b1  = (const float*)d_in[4];
    const float* W2l = (const float*)d_in[5];
    const float* W2r = (const float*)d_in[6];
    const float* b2  = (const float*)d_in[7];
    const float* W3l = (const float*)d_in[8];
    const float* W3r = (const float*)d_in[9];
    const float* b3  = (const float*)d_in[10];
    const float* TaW1 = (const float*)d_in[11];
    const float* TaB1 = (const float*)d_in[12];
    const float* TaW2 = (const float*)d_in[13];
    const float* TaB2 = (const float*)d_in[14];
    const float* TbW1 = (const float*)d_in[15];
    const float* TbB1 = (const float*)d_in[16];
    const float* TbW2 = (const float*)d_in[17];
    const float* TbB2 = (const float*)d_in[18];
    const float* l2w = (const float*)d_in[19];
    const float* l2b = (const float*)d_in[20];
    const float* l1w = (const float*)d_in[21];
    const float* l1b = (const float*)d_in[22];
    float* out = (float*)d_out;

    char* p = (char*)d_ws;
    size_t off = 0;
    auto alloc = [&](size_t bytes) -> void* {
        void* r = p + off;
        off = (off + bytes + 255) & ~(size_t)255;
        return r;
    };
    int*   deg       = (int*)  alloc((size_t)NN * 4);
    float* inv_deg   = (float*)alloc((size_t)NN * 4);
    float* dinv      = (float*)alloc((size_t)NN * 4);
    int*   row_start = (int*)  alloc((size_t)NN * 4);
    int*   cursor    = (int*)  alloc((size_t)NN * 4);
    int*   counter   = (int*)  alloc(256);
    int*   col       = (int*)  alloc((size_t)NE * 4);
    float* a8        = (float*)alloc((size_t)NN * 8 * 4);
    float* qA        = (float*)alloc((size_t)NN * 8 * 4);
    float* qB        = (float*)alloc((size_t)NN * 8 * 4);
    float* outa      = (float*)alloc((size_t)NN * 8 * 4);
    float* outb      = (float*)alloc((size_t)NN * 8 * 4);
    float* x1        = (float*)alloc((size_t)NN * 128 * 4);
    float* a128T     = (float*)alloc((size_t)NN * 128 * 4);
    float* x1T       = (float*)alloc((size_t)NN * 128 * 4);
    float* ylp       = (float*)alloc((size_t)NN * 8 * 4);
    float* yrp       = (float*)alloc((size_t)NN * 8 * 4);
    float* yl        = (float*)alloc((size_t)NN * 4);
    float* yr        = (float*)alloc((size_t)NN * 4);
    float* x1f       = (float*)alloc((size_t)NN * 4);
    float* x2s       = (float*)alloc((size_t)NN * 4);
    float* tA        = (float*)alloc((size_t)NN * 4);
    float* tB        = (float*)alloc((size_t)NN * 4);
    float* qb0       = (float*)alloc((size_t)NN * 4);
    float* q2a       = (float*)alloc((size_t)NN * 8);
    float* q2b       = (float*)alloc((size_t)NN * 8);
    float* ya        = (float*)alloc((size_t)NN * 4 * 4);
    float* yb        = (float*)alloc((size_t)NN * 10 * 4);

    // CSR build (reused by all edge passes)
    GL(k_init, NN, deg, cursor, counter);
    GL(k_deg, NE, dst, deg);
    GL(k_prep, NN, deg, inv_deg, dinv, row_start, counter);
    GL(k_fill, NE, src, dst, row_start, cursor, col);

    // SAGE1 (writes x1 row-major + x1T transposed directly)
    GL(k_meanprop8, (long)NN * 2, x, row_start, deg, inv_deg, col, a8);
    k_sage1<<<dim3((NN + 255) / 256, 16), dim3(256), 0, stream>>>(a8, x, W1l, W1r, b1, x1, x1T);
    // SAGE2+SAGE3-premul: fused aggregate+transpose, then fused GEMM+dot
    k_meanprop128T<<<dim3(NN / 32), dim3(1024), 0, stream>>>(x1, row_start, deg, inv_deg, col, a128T);
    k_sage2f<<<dim3(3136), dim3(256), 0, stream>>>(a128T, x1T, W2l, W2r, b2, W3l, W3r, ylp, yrp);
    GL(k_red8, NN, ylp, yrp, yl, yr);
    // SAGE3 scalar propagation
    GL(k_sage3, (long)NN * 8, yl, yr, row_start, deg, inv_deg, col, b3, x1f);

    // TAG layer 1 — shared P^k x chain, q-prescaled, fused projections
    GL(k_taginit, (long)NN * 8, x, TaW1, TbW1, dinv, outa, outb, qA);
    {
        float* qcur = qA;
        float* qnext = qB;
        for (int k = 1; k <= 9; ++k) {
            float* qout = (k < 9) ? qnext : nullptr;
            const float* Wa = (k <= 3) ? (TaW1 + (size_t)k * 64) : nullptr;
            GL(k_tagstep, (long)NN * 8, qcur, row_start, deg, dinv, col, qout,
               Wa, TbW1 + (size_t)k * 64, outa, outb, TaB1, TbB1,
               (k == 3) ? 1 : 0, (k == 9) ? 1 : 0);
            if (qout) { float* tmp = qcur; qcur = qnext; qnext = tmp; }
        }
    }

    // TAG layer 2 projections (both branches, one kernel)
    GL(k_tag2projAB, NN, outa, outb, TaW2, TbW2, ya, yb, dinv, q2a, qb0);

    // TAGb solo Horner steps 1..6; step 6 lands in q2a[2n+1]
    GL(k_symprop1n, (long)NN * 8, qb0, yb + 8 * NN, row_start, deg, dinv, col, tA, 1);
    GL(k_symprop1n, (long)NN * 8, tA,  yb + 7 * NN, row_start, deg, dinv, col, tB, 1);
    GL(k_symprop1n, (long)NN * 8, tB,  yb + 6 * NN, row_start, deg, dinv, col, tA, 1);
    GL(k_symprop1n, (long)NN * 8, tA,  yb + 5 * NN, row_start, deg, dinv, col, tB, 1);
    GL(k_symprop1n, (long)NN * 8, tB,  yb + 4 * NN, row_start, deg, dinv, col, tA, 1);
    GL(k_symprop1n, (long)NN * 8, tA,  yb + 3 * NN, row_start, deg, dinv, col, q2a + 1, 2);

    // fused a+b Horner steps (float2): q2a -> q2b -> q2a -> final combine
    GL(k_symprop2, (long)NN * 8, q2a, ya + 2 * NN, yb + 2 * NN, row_start, deg, dinv, col, q2b);
    GL(k_symprop2, (long)NN * 8, q2b, ya + 1 * NN, yb + 1 * NN, row_start, deg, dinv, col, q2a);
    GL(k_symprop2fin, (long)NN * 8, q2a, ya + 0 * NN, yb + 0 * NN, row_start, deg, dinv, col,
       TaB2, TbB2, x1f, l2w, l2b, l1w, l1b, out);
}

// Round 17
// 726.903 us; speedup vs baseline: 1.4191x; 1.0044x over previous
//
#include <hip/hip_runtime.h>

#define NN 100000
#define NE 1600000
#define TPB 256

// ---------------------------------------------------------------- CSR build
__global__ void k_init(int* __restrict__ deg, int* __restrict__ cursor, int* __restrict__ counter) {
    int i = blockIdx.x * TPB + threadIdx.x;
    if (i < NN) { deg[i] = 0; cursor[i] = 0; }
    if (i == 0) counter[0] = 0;
}

__global__ void k_deg(const int* __restrict__ dst, int* __restrict__ deg) {
    int e = blockIdx.x * TPB + threadIdx.x;
    if (e < NE) atomicAdd(&deg[dst[e]], 1);
}

// wave64 scan: one atomic per WAVE on the global counter
__global__ void k_prep(const int* __restrict__ deg, float* __restrict__ inv_deg,
                       float* __restrict__ dinv, int* __restrict__ row_start,
                       int* __restrict__ counter) {
    int i = blockIdx.x * TPB + threadIdx.x;
    int lane = threadIdx.x & 63;
    int d = (i < NN) ? deg[i] : 0;
    int incl = d;
    #pragma unroll
    for (int o = 1; o < 64; o <<= 1) {
        int v = __shfl_up(incl, o, 64);
        if (lane >= o) incl += v;
    }
    int total = __shfl(incl, 63, 64);
    int base = 0;
    if (lane == 63) base = atomicAdd(counter, total);
    base = __shfl(base, 63, 64);
    if (i < NN) {
        row_start[i] = base + incl - d;
        inv_deg[i] = d > 0 ? 1.0f / (float)d : 0.0f;
        dinv[i]    = d > 0 ? 1.0f / sqrtf((float)d) : 0.0f;
    }
}

__global__ void k_fill(const int* __restrict__ src, const int* __restrict__ dst,
                       const int* __restrict__ row_start, int* __restrict__ cursor,
                       int* __restrict__ col) {
    int e = blockIdx.x * TPB + threadIdx.x;
    if (e < NE) {
        int d = dst[e];
        int p = atomicAdd(&cursor[d], 1);
        col[row_start[d] + p] = src[e];
    }
}

// ---------------------------------------------------------------- propagation
// mean aggregation, 8 feats: 2 threads per node, float4 gathers, shfl combine
__global__ void k_meanprop8(const float* __restrict__ h, const int* __restrict__ row_start,
                            const int* __restrict__ deg, const float* __restrict__ inv_deg,
                            const int* __restrict__ col, float* __restrict__ out) {
    int t = blockIdx.x * TPB + threadIdx.x;
    if (t >= NN * 2) return;
    int n = t >> 1, half = t & 1;
    int rs = row_start[n], end = rs + deg[n];
    const float4* h4 = (const float4*)h;
    float4 s0 = make_float4(0,0,0,0), s1 = make_float4(0,0,0,0);
    int e = rs + half;
    for (; e + 2 < end; e += 4) {
        int c0 = col[e] * 2, c1 = col[e + 2] * 2;
        float4 a0 = h4[c0], a1 = h4[c0 + 1], b0 = h4[c1], b1 = h4[c1 + 1];
        s0.x += a0.x + b0.x; s0.y += a0.y + b0.y; s0.z += a0.z + b0.z; s0.w += a0.w + b0.w;
        s1.x += a1.x + b1.x; s1.y += a1.y + b1.y; s1.z += a1.z + b1.z; s1.w += a1.w + b1.w;
    }
    if (e < end) {
        int c0 = col[e] * 2;
        float4 a0 = h4[c0], a1 = h4[c0 + 1];
        s0.x += a0.x; s0.y += a0.y; s0.z += a0.z; s0.w += a0.w;
        s1.x += a1.x; s1.y += a1.y; s1.z += a1.z; s1.w += a1.w;
    }
    s0.x += __shfl_xor(s0.x, 1, 64); s0.y += __shfl_xor(s0.y, 1, 64);
    s0.z += __shfl_xor(s0.z, 1, 64); s0.w += __shfl_xor(s0.w, 1, 64);
    s1.x += __shfl_xor(s1.x, 1, 64); s1.y += __shfl_xor(s1.y, 1, 64);
    s1.z += __shfl_xor(s1.z, 1, 64); s1.w += __shfl_xor(s1.w, 1, 64);
    float w = inv_deg[n];
    float4 o = (half == 0) ? s0 : s1;
    o.x *= w; o.y *= w; o.z *= w; o.w *= w;
    ((float4*)out)[n * 2 + half] = o;
}

// mean aggregation, 128 feats, fused transpose: gather with balanced mapping
// (wave = 2 nodes x 32 f4), 8-deep independent loads in flight (latency-bound
// on L3 hits ~350cy; 8x16B outstanding covers it), LDS tile bounce, write
// a128T[f][n] coalesced. Block = 1024 thr = 32 nodes; NN = 3125*32 exactly.
__global__ __launch_bounds__(1024) void k_meanprop128T(const float* __restrict__ h,
                              const int* __restrict__ row_start,
                              const int* __restrict__ deg, const float* __restrict__ inv_deg,
                              const int* __restrict__ col, float* __restrict__ outT) {
    __shared__ float t[128][33];
    int n0 = blockIdx.x * 32;
    int tid = threadIdx.x;
    int nl = tid >> 5;          // 0..31 node local
    int f4 = tid & 31;          // 0..31 feature quad
    int n = n0 + nl;
    int rs = row_start[n], end = rs + deg[n];
    const float4* h4 = (const float4*)h;
    float4 s = make_float4(0.f, 0.f, 0.f, 0.f);
    int e = rs;
    for (; e + 7 < end; e += 8) {
        float4 v0 = h4[(size_t)col[e] * 32 + f4];
        float4 v1 = h4[(size_t)col[e + 1] * 32 + f4];
        float4 v2 = h4[(size_t)col[e + 2] * 32 + f4];
        float4 v3 = h4[(size_t)col[e + 3] * 32 + f4];
        float4 v4 = h4[(size_t)col[e + 4] * 32 + f4];
        float4 v5 = h4[(size_t)col[e + 5] * 32 + f4];
        float4 v6 = h4[(size_t)col[e + 6] * 32 + f4];
        float4 v7 = h4[(size_t)col[e + 7] * 32 + f4];
        s.x += ((v0.x + v1.x) + (v2.x + v3.x)) + ((v4.x + v5.x) + (v6.x + v7.x));
        s.y += ((v0.y + v1.y) + (v2.y + v3.y)) + ((v4.y + v5.y) + (v6.y + v7.y));
        s.z += ((v0.z + v1.z) + (v2.z + v3.z)) + ((v4.z + v5.z) + (v6.z + v7.z));
        s.w += ((v0.w + v1.w) + (v2.w + v3.w)) + ((v4.w + v5.w) + (v6.w + v7.w));
    }
    for (; e + 3 < end; e += 4) {
        float4 v0 = h4[(size_t)col[e] * 32 + f4];
        float4 v1 = h4[(size_t)col[e + 1] * 32 + f4];
        float4 v2 = h4[(size_t)col[e + 2] * 32 + f4];
        float4 v3 = h4[(size_t)col[e + 3] * 32 + f4];
        s.x += (v0.x + v1.x) + (v2.x + v3.x);
        s.y += (v0.y + v1.y) + (v2.y + v3.y);
        s.z += (v0.z + v1.z) + (v2.z + v3.z);
        s.w += (v0.w + v1.w) + (v2.w + v3.w);
    }
    for (; e < end; ++e) {
        float4 v = h4[(size_t)col[e] * 32 + f4];
        s.x += v.x; s.y += v.y; s.z += v.z; s.w += v.w;
    }
    float w = inv_deg[n];
    t[f4 * 4 + 0][nl] = s.x * w;
    t[f4 * 4 + 1][nl] = s.y * w;
    t[f4 * 4 + 2][nl] = s.z * w;
    t[f4 * 4 + 3][nl] = s.w * w;
    __syncthreads();
    int k = tid >> 3;           // 0..127 feature row
    int q = tid & 7;            // 0..7 node quad
    float4 v = make_float4(t[k][q * 4], t[k][q * 4 + 1], t[k][q * 4 + 2], t[k][q * 4 + 3]);
    *(float4*)(outT + (size_t)k * NN + n0 + q * 4) = v;
}

// fused TAG layer-1 step: 8 threads/node
__global__ void k_tagstep(const float* __restrict__ q, const int* __restrict__ row_start,
                          const int* __restrict__ deg, const float* __restrict__ dinv,
                          const int* __restrict__ col, float* __restrict__ qout,
                          const float* __restrict__ Wa, const float* __restrict__ Wb,
                          float* __restrict__ outa, float* __restrict__ outb,
                          const float* __restrict__ ba, const float* __restrict__ bb,
                          int fina, int finb) {
    int t = blockIdx.x * TPB + threadIdx.x;
    if (t >= NN * 8) return;
    int n = t >> 3, qd = t & 7;
    int half = qd & 1, epar = qd >> 1;
    int rs = row_start[n], end = rs + deg[n];
    const float4* q4 = (const float4*)q;
    float4 s = make_float4(0,0,0,0);
    int e = rs + epar;
    for (; e + 4 < end; e += 8) {
        int c0 = col[e] * 2 + half, c1 = col[e + 4] * 2 + half;
        float4 a = q4[c0], b = q4[c1];
        s.x += a.x + b.x; s.y += a.y + b.y; s.z += a.z + b.z; s.w += a.w + b.w;
    }
    if (e < end) {
        float4 a = q4[col[e] * 2 + half];
        s.x += a.x; s.y += a.y; s.z += a.z; s.w += a.w;
    }
    #pragma unroll
    for (int o = 2; o < 8; o <<= 1) {
        s.x += __shfl_xor(s.x, o, 64); s.y += __shfl_xor(s.y, o, 64);
        s.z += __shfl_xor(s.z, o, 64); s.w += __shfl_xor(s.w, o, 64);
    }
    float dn = dinv[n];
    float m0 = s.x * dn, m1 = s.y * dn, m2 = s.z * dn, m3 = s.w * dn;
    if (qout && epar == 0) {
        ((float4*)qout)[n * 2 + half] = make_float4(m0 * dn, m1 * dn, m2 * dn, m3 * dn);
    }
    float o0 = __shfl_xor(m0, 1, 64), o1 = __shfl_xor(m1, 1, 64);
    float o2 = __shfl_xor(m2, 1, 64), o3 = __shfl_xor(m3, 1, 64);
    float h[8];
    if (half) {
        h[0] = o0; h[1] = o1; h[2] = o2; h[3] = o3;
        h[4] = m0; h[5] = m1; h[6] = m2; h[7] = m3;
    } else {
        h[0] = m0; h[1] = m1; h[2] = m2; h[3] = m3;
        h[4] = o0; h[5] = o1; h[6] = o2; h[7] = o3;
    }
    int f = qd;
    if (Wa) {
        float v = outa[(size_t)n * 8 + f];
        #pragma unroll
        for (int j = 0; j < 8; ++j) v += h[j] * Wa[j * 8 + f];
        if (fina) v = fmaxf(v + ba[f], 0.f);
        outa[(size_t)n * 8 + f] = v;
    }
    {
        float v = outb[(size_t)n * 8 + f];
        #pragma unroll
        for (int j = 0; j < 8; ++j) v += h[j] * Wb[j * 8 + f];
        if (finb) v = fmaxf(v + bb[f], 0.f);
        outb[(size_t)n * 8 + f] = v;
    }
}

// scalar sym-prop Horner step, 8 thr/node, q-prescaled input (1 load/edge).
__global__ void k_symprop1n(const float* __restrict__ qin, const float* __restrict__ yk,
                            const int* __restrict__ row_start, const int* __restrict__ deg,
                            const float* __restrict__ dinv, const int* __restrict__ col,
                            float* __restrict__ qout, int qstride) {
    int t = blockIdx.x * TPB + threadIdx.x;
    if (t >= NN * 8) return;
    int n = t >> 3, qd = t & 7;
    int rs = row_start[n], d = deg[n];
    float s = 0.f;
    for (int e = rs + qd; e < rs + d; e += 8) s += qin[col[e]];
    s += __shfl_xor(s, 1, 64);
    s += __shfl_xor(s, 2, 64);
    s += __shfl_xor(s, 4, 64);
    if (qd == 0) {
        float dn = dinv[n];
        qout[(size_t)n * qstride] = dn * (dn * s + yk[n]);
    }
}

// fused 2-channel sym-prop Horner step, 8 thr/node, float2 loads
__global__ void k_symprop2(const float* __restrict__ q2in, const float* __restrict__ yka,
                           const float* __restrict__ ykb, const int* __restrict__ row_start,
                           const int* __restrict__ deg, const float* __restrict__ dinv,
                           const int* __restrict__ col, float* __restrict__ q2out) {
    int t = blockIdx.x * TPB + threadIdx.x;
    if (t >= NN * 8) return;
    int n = t >> 3, qd = t & 7;
    int rs = row_start[n], d = deg[n];
    const float2* q2 = (const float2*)q2in;
    float sa = 0.f, sb = 0.f;
    for (int e = rs + qd; e < rs + d; e += 8) {
        float2 v = q2[col[e]];
        sa += v.x; sb += v.y;
    }
    sa += __shfl_xor(sa, 1, 64); sa += __shfl_xor(sa, 2, 64); sa += __shfl_xor(sa, 4, 64);
    sb += __shfl_xor(sb, 1, 64); sb += __shfl_xor(sb, 2, 64); sb += __shfl_xor(sb, 4, 64);
    if (qd == 0) {
        float dn = dinv[n];
        ((float2*)q2out)[n] = make_float2(dn * (dn * sa + yka[n]),
                                          dn * (dn * sb + ykb[n]));
    }
}

// final 2-channel sym-prop step + full output combine
__global__ void k_symprop2fin(const float* __restrict__ q2in, const float* __restrict__ yka,
                              const float* __restrict__ ykb, const int* __restrict__ row_start,
                              const int* __restrict__ deg, const float* __restrict__ dinv,
                              const int* __restrict__ col,
                              const float* __restrict__ biasa, const float* __restrict__ biasb,
                              const float* __restrict__ x1f,
                              const float* __restrict__ l2w, const float* __restrict__ l2b,
                              const float* __restrict__ l1w, const float* __restrict__ l1b,
                              float* __restrict__ out) {
    int t = blockIdx.x * TPB + threadIdx.x;
    if (t >= NN * 8) return;
    int n = t >> 3, qd = t & 7;
    int rs = row_start[n], d = deg[n];
    const float2* q2 = (const float2*)q2in;
    float sa = 0.f, sb = 0.f;
    for (int e = rs + qd; e < rs + d; e += 8) {
        float2 v = q2[col[e]];
        sa += v.x; sb += v.y;
    }
    sa += __shfl_xor(sa, 1, 64); sa += __shfl_xor(sa, 2, 64); sa += __shfl_xor(sa, 4, 64);
    sb += __shfl_xor(sb, 1, 64); sb += __shfl_xor(sb, 2, 64); sb += __shfl_xor(sb, 4, 64);
    if (qd == 0) {
        float dn = dinv[n];
        float x2 = fmaxf(dn * sa + yka[n] + biasa[0], 0.f);
        float x3 = fmaxf(dn * sb + ykb[n] + biasb[0], 0.f);
        float x23 = fmaxf(x2 * l2w[0] + x3 * l2w[1] + l2b[0], 0.f);
        out[n] = fmaxf(x1f[n] * l1w[0] + x23 * l1w[1] + l1b[0], 0.f);
    }
}

// sum the 8 partial dots from k_sage2f
__global__ void k_red8(const float* __restrict__ ylp, const float* __restrict__ yrp,
                       float* __restrict__ yl, float* __restrict__ yr) {
    int n = blockIdx.x * TPB + threadIdx.x;
    if (n >= NN) return;
    float sl = 0.f, sr = 0.f;
    #pragma unroll
    for (int j = 0; j < 8; ++j) {
        sl += ylp[(size_t)j * NN + n];
        sr += yrp[(size_t)j * NN + n];
    }
    yl[n] = sl;
    yr[n] = sr;
}

// mean scalar propagation + SAGE3 epilogue, 8 thr/node
__global__ void k_sage3(const float* __restrict__ yl, const float* __restrict__ yr,
                        const int* __restrict__ row_start, const int* __restrict__ deg,
                        const float* __restrict__ inv_deg, const int* __restrict__ col,
                        const float* __restrict__ b3, float* __restrict__ x1f) {
    int t = blockIdx.x * TPB + threadIdx.x;
    if (t >= NN * 8) return;
    int n = t >> 3, q = t & 7;
    int rs = row_start[n], d = deg[n];
    float s = 0.f;
    for (int e = rs + q; e < rs + d; e += 8) s += yl[col[e]];
    s += __shfl_xor(s, 1, 64);
    s += __shfl_xor(s, 2, 64);
    s += __shfl_xor(s, 4, 64);
    if (q == 0) x1f[n] = fmaxf(s * inv_deg[n] + yr[n] + b3[0], 0.f);
}

// ---------------------------------------------------------------- dense transforms
// SAGE1: lane = node, og-block from grid.y; writes x1 row-major + x1T transposed
__global__ __launch_bounds__(256) void k_sage1(const float* __restrict__ a8,
                        const float* __restrict__ x,
                        const float* __restrict__ W1l, const float* __restrict__ W1r,
                        const float* __restrict__ b1, float* __restrict__ x1,
                        float* __restrict__ x1T) {
    int n = blockIdx.x * 256 + threadIdx.x;
    int og = blockIdx.y * 8;
    int nc = (n < NN) ? n : (NN - 1);
    float acc[8];
    #pragma unroll
    for (int j = 0; j < 8; ++j) acc[j] = b1[og + j];
    const float* ar = a8 + (size_t)nc * 8;
    const float* xr = x + (size_t)nc * 8;
    #pragma unroll
    for (int k = 0; k < 8; ++k) {
        float av = ar[k], xv = xr[k];
        const float4* wl = (const float4*)(W1l + k * 128 + og);
        const float4* wr = (const float4*)(W1r + k * 128 + og);
        float4 l0 = wl[0], l1 = wl[1], r0 = wr[0], r1 = wr[1];
        acc[0] += av * l0.x + xv * r0.x;
        acc[1] += av * l0.y + xv * r0.y;
        acc[2] += av * l0.z + xv * r0.z;
        acc[3] += av * l0.w + xv * r0.w;
        acc[4] += av * l1.x + xv * r1.x;
        acc[5] += av * l1.y + xv * r1.y;
        acc[6] += av * l1.z + xv * r1.z;
        acc[7] += av * l1.w + xv * r1.w;
    }
    if (n < NN) {
        #pragma unroll
        for (int j = 0; j < 8; ++j) acc[j] = fmaxf(acc[j], 0.f);
        *(float4*)(x1 + (size_t)n * 128 + og)     = make_float4(acc[0], acc[1], acc[2], acc[3]);
        *(float4*)(x1 + (size_t)n * 128 + og + 4) = make_float4(acc[4], acc[5], acc[6], acc[7]);
        #pragma unroll
        for (int j = 0; j < 8; ++j)
            x1T[(size_t)(og + j) * NN + n] = acc[j];
    }
}

// SAGE2 fused with SAGE3 pre-multiply: R8 geometry (og-eighths, acc[16],
// 3136 blocks, XCD swizzle) + explicit 4-deep activation prefetch pipeline
// (validated R16: sage2f dropped below top-5). Static indexing only.
__global__ __launch_bounds__(256) void k_sage2f(const float* __restrict__ aT,
        const float* __restrict__ xT, const float* __restrict__ W2l,
        const float* __restrict__ W2r, const float* __restrict__ b2,
        const float* __restrict__ W3l, const float* __restrict__ W3r,
        float* __restrict__ ylp, float* __restrict__ yrp) {
    int xcd = blockIdx.x & 7;
    int s = blockIdx.x >> 3;            // 0..391
    int xblk = xcd * 49 + (s >> 3);     // 0..391 (392 node-blocks)
    int ogq = s & 7;
    int og = ogq * 16;
    int n0 = xblk * 256 + threadIdx.x;
    int n = (n0 < NN) ? n0 : (NN - 1);
    float acc[16];
    #pragma unroll
    for (int j = 0; j < 16; ++j) acc[j] = b2[og + j];
    const float* ap = aT + n;
    const float* xp = xT + n;
    const float* wlp = W2l + og;
    const float* wrp = W2r + og;
    float an[4], xn[4];
    #pragma unroll
    for (int i = 0; i < 4; ++i) {
        an[i] = ap[0]; xn[i] = xp[0];
        ap += NN; xp += NN;
    }
    for (int k = 0; k < 128; k += 4) {
        float ac[4], xc[4];
        #pragma unroll
        for (int i = 0; i < 4; ++i) { ac[i] = an[i]; xc[i] = xn[i]; }
        if (k + 4 < 128) {
            #pragma unroll
            for (int i = 0; i < 4; ++i) {
                an[i] = ap[0]; xn[i] = xp[0];
                ap += NN; xp += NN;
            }
        }
        #pragma unroll
        for (int i = 0; i < 4; ++i) {
            const float4* wl4 = (const float4*)(wlp + ((k + i) << 7));
            const float4* wr4 = (const float4*)(wrp + ((k + i) << 7));
            float a = ac[i], xv = xc[i];
            #pragma unroll
            for (int q = 0; q < 4; ++q) {
                float4 wl = wl4[q], wr = wr4[q];
                acc[q * 4 + 0] += a * wl.x + xv * wr.x;
                acc[q * 4 + 1] += a * wl.y + xv * wr.y;
                acc[q * 4 + 2] += a * wl.z + xv * wr.z;
                acc[q * 4 + 3] += a * wl.w + xv * wr.w;
            }
        }
    }
    float pl = 0.f, pr = 0.f;
    #pragma unroll
    for (int j = 0; j < 16; ++j) {
        float v = fmaxf(acc[j], 0.f);
        pl += v * W3l[og + j];
        pr += v * W3r[og + j];
    }
    if (n0 < NN) {
        ylp[(size_t)ogq * NN + n0] = pl;
        yrp[(size_t)ogq * NN + n0] = pr;
    }
}

// TAG k=0 term for both branches + q0 = dinv[n]*x[n]
__global__ void k_taginit(const float* __restrict__ x, const float* __restrict__ TaW,
                          const float* __restrict__ TbW, const float* __restrict__ dinv,
                          float* __restrict__ outa, float* __restrict__ outb,
                          float* __restrict__ q0) {
    int t = blockIdx.x * TPB + threadIdx.x;
    if (t >= NN * 8) return;
    int n = t >> 3, o = t & 7;
    const float* xr = x + (size_t)n * 8;
    float sa = 0.f, sb = 0.f;
    #pragma unroll
    for (int j = 0; j < 8; ++j) {
        float v = xr[j];
        sa += v * TaW[j * 8 + o];
        sb += v * TbW[j * 8 + o];
    }
    outa[t] = sa;
    outb[t] = sb;
    q0[t] = xr[o] * dinv[n];
}

// both TAG layer-2 projections in one kernel; last k of each chain pre-scaled
__global__ void k_tag2projAB(const float* __restrict__ outa, const float* __restrict__ outb,
                             const float* __restrict__ TaW2, const float* __restrict__ TbW2,
                             float* __restrict__ ya, float* __restrict__ yb,
                             const float* __restrict__ dinv,
                             float* __restrict__ q2a, float* __restrict__ qb0) {
    int n = blockIdx.x * TPB + threadIdx.x;
    if (n >= NN) return;
    float dn = dinv[n];
    float ha[8], hb[8];
    #pragma unroll
    for (int j = 0; j < 8; ++j) ha[j] = outa[(size_t)n * 8 + j];
    #pragma unroll
    for (int j = 0; j < 8; ++j) hb[j] = outb[(size_t)n * 8 + j];
    #pragma unroll
    for (int k = 0; k < 4; ++k) {
        float s = 0.f;
        #pragma unroll
        for (int j = 0; j < 8; ++j) s += ha[j] * TaW2[k * 8 + j];
        if (k == 3) q2a[(size_t)n * 2] = s * dn;
        else        ya[(size_t)k * NN + n] = s;
    }
    #pragma unroll
    for (int k = 0; k < 10; ++k) {
        float s = 0.f;
        #pragma unroll
        for (int j = 0; j < 8; ++j) s += hb[j] * TbW2[k * 8 + j];
        if (k == 9) qb0[n] = s * dn;
        else        yb[(size_t)k * NN + n] = s;
    }
}

// ---------------------------------------------------------------- host launch
#define GL(kern, n, ...) \
    kern<<<dim3((unsigned)(((long)(n) + TPB - 1) / TPB)), dim3(TPB), 0, stream>>>(__VA_ARGS__)

extern "C" void kernel_launch(void* const* d_in, const int* in_sizes, int n_in,
                              void* d_out, int out_size, void* d_ws, size_t ws_size,
                              hipStream_t stream) {
    (void)in_sizes; (void)n_in; (void)out_size; (void)ws_size;
    const float* x   = (const float*)d_in[0];
    const int*   ei  = (const int*)d_in[1];
    const int*   src = ei;
    const int*   dst = ei + NE;
    const float* W1l = (const float*)d_in[2];
    const float* W1r = (const float*)d_in[3];
    const float* b1  = (const float*)d_in[4];
    const float* W2l = (const float*)d_in[5];
    const float* W2r = (const float*)d_in[6];
    const float* b2  = (const float*)d_in[7];
    const float* W3l = (const float*)d_in[8];
    const float* W3r = (const float*)d_in[9];
    const float* b3  = (const float*)d_in[10];
    const float* TaW1 = (const float*)d_in[11];
    const float* TaB1 = (const float*)d_in[12];
    const float* TaW2 = (const float*)d_in[13];
    const float* TaB2 = (const float*)d_in[14];
    const float* TbW1 = (const float*)d_in[15];
    const float* TbB1 = (const float*)d_in[16];
    const float* TbW2 = (const float*)d_in[17];
    const float* TbB2 = (const float*)d_in[18];
    const float* l2w = (const float*)d_in[19];
    const float* l2b = (const float*)d_in[20];
    const float* l1w = (const float*)d_in[21];
    const float* l1b = (const float*)d_in[22];
    float* out = (float*)d_out;

    char* p = (char*)d_ws;
    size_t off = 0;
    auto alloc = [&](size_t bytes) -> void* {
        void* r = p + off;
        off = (off + bytes + 255) & ~(size_t)255;
        return r;
    };
    int*   deg       = (int*)  alloc((size_t)NN * 4);
    float* inv_deg   = (float*)alloc((size_t)NN * 4);
    float* dinv      = (float*)alloc((size_t)NN * 4);
    int*   row_start = (int*)  alloc((size_t)NN * 4);
    int*   cursor    = (int*)  alloc((size_t)NN * 4);
    int*   counter   = (int*)  alloc(256);
    int*   col       = (int*)  alloc((size_t)NE * 4);
    float* a8        = (float*)alloc((size_t)NN * 8 * 4);
    float* qA        = (float*)alloc((size_t)NN * 8 * 4);
    float* qB        = (float*)alloc((size_t)NN * 8 * 4);
    float* outa      = (float*)alloc((size_t)NN * 8 * 4);
    float* outb      = (float*)alloc((size_t)NN * 8 * 4);
    float* x1        = (float*)alloc((size_t)NN * 128 * 4);
    float* a128T     = (float*)alloc((size_t)NN * 128 * 4);
    float* x1T       = (float*)alloc((size_t)NN * 128 * 4);
    float* ylp       = (float*)alloc((size_t)NN * 8 * 4);
    float* yrp       = (float*)alloc((size_t)NN * 8 * 4);
    float* yl        = (float*)alloc((size_t)NN * 4);
    float* yr        = (float*)alloc((size_t)NN * 4);
    float* x1f       = (float*)alloc((size_t)NN * 4);
    float* x2s       = (float*)alloc((size_t)NN * 4);
    float* tA        = (float*)alloc((size_t)NN * 4);
    float* tB        = (float*)alloc((size_t)NN * 4);
    float* qb0       = (float*)alloc((size_t)NN * 4);
    float* q2a       = (float*)alloc((size_t)NN * 8);
    float* q2b       = (float*)alloc((size_t)NN * 8);
    float* ya        = (float*)alloc((size_t)NN * 4 * 4);
    float* yb        = (float*)alloc((size_t)NN * 10 * 4);

    // CSR build (reused by all edge passes)
    GL(k_init, NN, deg, cursor, counter);
    GL(k_deg, NE, dst, deg);
    GL(k_prep, NN, deg, inv_deg, dinv, row_start, counter);
    GL(k_fill, NE, src, dst, row_start, cursor, col);

    // SAGE1 (writes x1 row-major + x1T transposed directly)
    GL(k_meanprop8, (long)NN * 2, x, row_start, deg, inv_deg, col, a8);
    k_sage1<<<dim3((NN + 255) / 256, 16), dim3(256), 0, stream>>>(a8, x, W1l, W1r, b1, x1, x1T);
    // SAGE2+SAGE3-premul: fused aggregate+transpose, then fused GEMM+dot
    k_meanprop128T<<<dim3(NN / 32), dim3(1024), 0, stream>>>(x1, row_start, deg, inv_deg, col, a128T);
    k_sage2f<<<dim3(3136), dim3(256), 0, stream>>>(a128T, x1T, W2l, W2r, b2, W3l, W3r, ylp, yrp);
    GL(k_red8, NN, ylp, yrp, yl, yr);
    // SAGE3 scalar propagation
    GL(k_sage3, (long)NN * 8, yl, yr, row_start, deg, inv_deg, col, b3, x1f);

    // TAG layer 1 — shared P^k x chain, q-prescaled, fused projections
    GL(k_taginit, (long)NN * 8, x, TaW1, TbW1, dinv, outa, outb, qA);
    {
        float* qcur = qA;
        float* qnext = qB;
        for (int k = 1; k <= 9; ++k) {
            float* qout = (k < 9) ? qnext : nullptr;
            const float* Wa = (k <= 3) ? (TaW1 + (size_t)k * 64) : nullptr;
            GL(k_tagstep, (long)NN * 8, qcur, row_start, deg, dinv, col, qout,
               Wa, TbW1 + (size_t)k * 64, outa, outb, TaB1, TbB1,
               (k == 3) ? 1 : 0, (k == 9) ? 1 : 0);
            if (qout) { float* tmp = qcur; qcur = qnext; qnext = tmp; }
        }
    }

    // TAG layer 2 projections (both branches, one kernel)
    GL(k_tag2projAB, NN, outa, outb, TaW2, TbW2, ya, yb, dinv, q2a, qb0);

    // TAGb solo Horner steps 1..6; step 6 lands in q2a[2n+1]
    GL(k_symprop1n, (long)NN * 8, qb0, yb + 8 * NN, row_start, deg, dinv, col, tA, 1);
    GL(k_symprop1n, (long)NN * 8, tA,  yb + 7 * NN, row_start, deg, dinv, col, tB, 1);
    GL(k_symprop1n, (long)NN * 8, tB,  yb + 6 * NN, row_start, deg, dinv, col, tA, 1);
    GL(k_symprop1n, (long)NN * 8, tA,  yb + 5 * NN, row_start, deg, dinv, col, tB, 1);
    GL(k_symprop1n, (long)NN * 8, tB,  yb + 4 * NN, row_start, deg, dinv, col, tA, 1);
    GL(k_symprop1n, (long)NN * 8, tA,  yb + 3 * NN, row_start, deg, dinv, col, q2a + 1, 2);

    // fused a+b Horner steps (float2): q2a -> q2b -> q2a -> final combine
    GL(k_symprop2, (long)NN * 8, q2a, ya + 2 * NN, yb + 2 * NN, row_start, deg, dinv, col, q2b);
    GL(k_symprop2, (long)NN * 8, q2b, ya + 1 * NN, yb + 1 * NN, row_start, deg, dinv, col, q2a);
    GL(k_symprop2fin, (long)NN * 8, q2a, ya + 0 * NN, yb + 0 * NN, row_start, deg, dinv, col,
       TaB2, TbB2, x1f, l2w, l2b, l1w, l1b, out);
}